// Round 8
// baseline (111.747 us; speedup 1.0000x reference)
//
#include <hip/hip_runtime.h>
#include <math.h>

// B=2, N=512, D=64, DH=64
#define NN 512

typedef float f4 __attribute__((ext_vector_type(4)));  // native vec for nontemporal builtins

// ---------------- precompute weight products (runs once per launch, 3 blocks) ----------------
// m=0: M_P  = Wkn @ Wqe^T ; c_P  = bkn @ Wqe^T ; vq0 = 0.125*(Wkn @ bqe) ; s0 = 0.125*(bqe.bkn)
// m=1: M_ke = Wvn @ Wke   ; c_ke = bvn @ Wke
// m=2: M_ve = Wvn @ Wve   ; c_ve = bvn @ Wve
__global__ __launch_bounds__(256) void precompute_kernel(
    const float* __restrict__ Wkn, const float* __restrict__ bkn,
    const float* __restrict__ Wvn, const float* __restrict__ bvn,
    const float* __restrict__ Wqe, const float* __restrict__ bqe,
    const float* __restrict__ Wke, const float* __restrict__ Wve,
    float* __restrict__ M_P, float* __restrict__ c_P,
    float* __restrict__ M_ke, float* __restrict__ c_ke,
    float* __restrict__ M_ve, float* __restrict__ c_ve,
    float* __restrict__ vq0, float* __restrict__ s0p)
{
    const int m = blockIdx.x;
    const int t = threadIdx.x;
    __shared__ float As[64 * 65];   // A row-major, padded
    __shared__ float Bs[64 * 65];   // Bs[b][k] = B-operand with dot axis k
    __shared__ float va[64], vb[64];
    const float* A  = (m == 0) ? Wkn : Wvn;
    const float* aV = (m == 0) ? bkn : bvn;
    const float* B  = (m == 0) ? Wqe : (m == 1 ? Wke : Wve);

#pragma unroll
    for (int p = 0; p < 16; ++p) {
        const int idx = p * 256 + t;           // 4096 elements
        const int r = idx >> 6, cc = idx & 63;
        As[r * 65 + cc] = A[idx];
        if (m == 0) Bs[r * 65 + cc] = B[idx];  // Wqe[b][k] already dot-over-k layout
        else        Bs[cc * 65 + r] = B[idx];  // transpose Wke/Wve: Bs[b][k] = B[k][b]
    }
    if (t < 64) { va[t] = aV[t]; vb[t] = bqe[t]; }
    __syncthreads();

    const int b = t & 63, g = t >> 6;          // thread: column b, 16 rows (g*16..)
    float acc[16];
#pragma unroll
    for (int aa = 0; aa < 16; ++aa) acc[aa] = 0.f;
    for (int k = 0; k < 64; ++k) {
        const float bv = Bs[b * 65 + k];       // banks (b+k)%32: conflict-free
#pragma unroll
        for (int aa = 0; aa < 16; ++aa)        // As read is wave-broadcast
            acc[aa] = fmaf(As[(g * 16 + aa) * 65 + k], bv, acc[aa]);
    }
    float* M = (m == 0) ? M_P : (m == 1 ? M_ke : M_ve);
#pragma unroll
    for (int aa = 0; aa < 16; ++aa)
        M[(g * 16 + aa) * 64 + b] = acc[aa];

    if (t < 64) {
        float cb = 0.f;
        for (int k = 0; k < 64; ++k) cb = fmaf(va[k], Bs[t * 65 + k], cb);
        float* C = (m == 0) ? c_P : (m == 1 ? c_ke : c_ve);
        C[t] = cb;
        if (m == 0) {
            float q = 0.f;
            for (int k = 0; k < 64; ++k) q = fmaf(As[t * 65 + k], vb[k], q);
            vq0[t] = q * 0.125f;
        }
    }
    if (m == 0 && t == 0) {
        float s = 0.f;
        for (int k = 0; k < 64; ++k) s += vb[k] * va[k];
        *s0p = s * 0.125f;
    }
}

// ---------------- tiled 3-way projection: 32 rows/block, weights in LDS ----------------
__global__ __launch_bounds__(256) void proj3_tiled(
    const float* __restrict__ in,
    const float* __restrict__ W0, const float* __restrict__ b0,
    const float* __restrict__ W1, const float* __restrict__ b1,
    const float* __restrict__ W2, const float* __restrict__ b2,
    float* __restrict__ o0, float* __restrict__ o1, float* __restrict__ o2)
{
    const int t = threadIdx.x;
    const int rb = blockIdx.x * 32;
    __shared__ float Ws0[4096], Ws1[4096], Ws2[4096];
    __shared__ float xs[2048];
    __shared__ float bs0[64], bs1[64], bs2[64];
#pragma unroll
    for (int p = 0; p < 4; ++p) {
        const int idx = p * 256 + t;
        ((f4*)Ws0)[idx] = ((const f4*)W0)[idx];
        ((f4*)Ws1)[idx] = ((const f4*)W1)[idx];
        ((f4*)Ws2)[idx] = ((const f4*)W2)[idx];
    }
    ((f4*)xs)[t]       = ((const f4*)(in + rb * 64))[t];
    ((f4*)xs)[t + 256] = ((const f4*)(in + rb * 64))[t + 256];
    if (t < 64) { bs0[t] = b0[t]; bs1[t] = b1[t]; bs2[t] = b2[t]; }
    __syncthreads();

    const int d = t & 63, g = t >> 6;          // wave g owns rows g*8..g*8+7
    float a0[8], a1[8], a2[8];
#pragma unroll
    for (int r = 0; r < 8; ++r) { a0[r] = bs0[d]; a1[r] = bs1[d]; a2[r] = bs2[d]; }
    for (int k4 = 0; k4 < 16; ++k4) {
        float w0[4], w1[4], w2[4];
#pragma unroll
        for (int kk = 0; kk < 4; ++kk) {
            w0[kk] = Ws0[(k4 * 4 + kk) * 64 + d];
            w1[kk] = Ws1[(k4 * 4 + kk) * 64 + d];
            w2[kk] = Ws2[(k4 * 4 + kk) * 64 + d];
        }
#pragma unroll
        for (int r = 0; r < 8; ++r) {
            const f4 xv = ((const f4*)xs)[(g * 8 + r) * 16 + k4];  // wave-broadcast b128
            a0[r] = fmaf(xv.x, w0[0], fmaf(xv.y, w0[1], fmaf(xv.z, w0[2], fmaf(xv.w, w0[3], a0[r]))));
            a1[r] = fmaf(xv.x, w1[0], fmaf(xv.y, w1[1], fmaf(xv.z, w1[2], fmaf(xv.w, w1[3], a1[r]))));
            a2[r] = fmaf(xv.x, w2[0], fmaf(xv.y, w2[1], fmaf(xv.z, w2[2], fmaf(xv.w, w2[3], a2[r]))));
        }
    }
#pragma unroll
    for (int r = 0; r < 8; ++r) {
        o0[(rb + g * 8 + r) * 64 + d] = a0[r];
        o1[(rb + g * 8 + r) * 64 + d] = a1[r];
        o2[(rb + g * 8 + r) * 64 + d] = a2[r];
    }
}

// ---------- node-to-node self attention (512 thr): x_hat = softmax(QK^T/8) @ V ----------
__global__ __launch_bounds__(512) void selfattn_kernel(
    const float* __restrict__ Q, const float* __restrict__ K,
    const float* __restrict__ V, float* __restrict__ xhat)
{
    const int row = blockIdx.x;            // b*512 + n
    const int b = row >> 9;
    const int t = threadIdx.x;
    __shared__ float qr[64];
    __shared__ float p[512];
    __shared__ float red[512];
    if (t < 64) qr[t] = Q[row * 64 + t];
    __syncthreads();

    // scores: one thread per key row m (per-thread dot, no shuffles)
    {
        const int m = t;
        const f4* kr = (const f4*)(K + (size_t)(b * NN + m) * 64);
        const f4* qq = (const f4*)qr;
        float sp[4] = {0.f, 0.f, 0.f, 0.f};
#pragma unroll
        for (int u = 0; u < 16; ++u) {
            const f4 w = kr[u];
            const f4 qv = qq[u];
            sp[u & 3] += qv.x * w.x + qv.y * w.y + qv.z * w.z + qv.w * w.w;
        }
        p[m] = ((sp[0] + sp[1]) + (sp[2] + sp[3])) * 0.125f;
    }
    __syncthreads();

    const int lane = t & 63, w = t >> 6;
    const float v0 = p[t];
    float m = v0;
#pragma unroll
    for (int o = 1; o < 64; o <<= 1) m = fmaxf(m, __shfl_xor(m, o));
    if (lane == 0) red[w] = m;
    __syncthreads();
    float mx = red[0];
#pragma unroll
    for (int z = 1; z < 8; ++z) mx = fmaxf(mx, red[z]);
    const float e0 = expf(v0 - mx);
    float ss = e0;
#pragma unroll
    for (int o = 1; o < 64; o <<= 1) ss += __shfl_xor(ss, o);
    if (lane == 0) red[8 + w] = ss;
    __syncthreads();
    const float inv = 1.f / (red[8] + red[9] + red[10] + red[11]
                           + red[12] + red[13] + red[14] + red[15]);
    p[t] = e0;
    __syncthreads();

    const int d = t & 63, q = t >> 6;
    float acc = 0.f;
    const int j0 = q * 64;
    for (int j = j0; j < j0 + 64; ++j)
        acc = fmaf(p[j], V[(b * NN + j) * 64 + d], acc);
    red[t] = acc;
    __syncthreads();
    if (t < 64) {
        float s8 = 0.f;
#pragma unroll
        for (int z = 0; z < 8; ++z) s8 += red[t + z * 64];
        xhat[row * 64 + t] = s8 * inv;
    }
}

// ---------------- fused affine maps of xhat: Qn, Vn, P, VnWke, VnWve, q0 ----------------
__global__ __launch_bounds__(256) void affine5_kernel(
    const float* __restrict__ xhat,
    const float* __restrict__ Wqn, const float* __restrict__ bqn,
    const float* __restrict__ Wvn, const float* __restrict__ bvn,
    const float* __restrict__ M_P, const float* __restrict__ c_P,
    const float* __restrict__ M_ke, const float* __restrict__ c_ke,
    const float* __restrict__ M_ve, const float* __restrict__ c_ve,
    const float* __restrict__ vq0, const float* __restrict__ s0p,
    float* __restrict__ Qn, float* __restrict__ Vn, float* __restrict__ P,
    float* __restrict__ VnWke, float* __restrict__ VnWve, float* __restrict__ q0)
{
    const int t = threadIdx.x;
    const int rb = blockIdx.x * 32;
    const int m = blockIdx.y;
    const float* W; const float* c; float* o;
    if (m == 0)      { W = Wqn;  c = bqn;  o = Qn; }
    else if (m == 1) { W = Wvn;  c = bvn;  o = Vn; }
    else if (m == 2) { W = M_P;  c = c_P;  o = P; }
    else if (m == 3) { W = M_ke; c = c_ke; o = VnWke; }
    else             { W = M_ve; c = c_ve; o = VnWve; }
    __shared__ float Ws[4096], xs[2048], cs[64], vq0s[64];
#pragma unroll
    for (int p = 0; p < 4; ++p) ((f4*)Ws)[p * 256 + t] = ((const f4*)W)[p * 256 + t];
    ((f4*)xs)[t]       = ((const f4*)(xhat + rb * 64))[t];
    ((f4*)xs)[t + 256] = ((const f4*)(xhat + rb * 64))[t + 256];
    if (t < 64) { cs[t] = c[t]; if (m == 0) vq0s[t] = vq0[t]; }
    __syncthreads();

    const int d = t & 63, g = t >> 6;
    float acc[8];
#pragma unroll
    for (int r = 0; r < 8; ++r) acc[r] = cs[d];
    for (int k4 = 0; k4 < 16; ++k4) {
        float w[4];
#pragma unroll
        for (int kk = 0; kk < 4; ++kk) w[kk] = Ws[(k4 * 4 + kk) * 64 + d];
#pragma unroll
        for (int r = 0; r < 8; ++r) {
            const f4 xv = ((const f4*)xs)[(g * 8 + r) * 16 + k4];
            acc[r] = fmaf(xv.x, w[0], fmaf(xv.y, w[1], fmaf(xv.z, w[2], fmaf(xv.w, w[3], acc[r]))));
        }
    }
#pragma unroll
    for (int r = 0; r < 8; ++r) o[(rb + g * 8 + r) * 64 + d] = acc[r];

    if (m == 0) {
        // q0[rb+row] = s0 + xhat_row . vq0 ; row = t>>3, 8-lane segments
        const int row = t >> 3, seg = t & 7;
        float part = 0.f;
#pragma unroll
        for (int kk = 0; kk < 8; ++kk)
            part = fmaf(xs[row * 64 + seg * 8 + kk], vq0s[seg * 8 + kk], part);
        part += __shfl_xor(part, 1);
        part += __shfl_xor(part, 2);
        part += __shfl_xor(part, 4);
        if (seg == 0) q0[rb + row] = part + s0p[0];
    }
}

// ---------- pure streaming edge pass: 8192 blocks x 256 thr, no LDS, no barriers ----------
__global__ __launch_bounds__(256) void edge_kernel(
    const float* __restrict__ e, const float* __restrict__ P,
    const float* __restrict__ q0, const float* __restrict__ Vn,
    float* __restrict__ e_new, float* __restrict__ AiBuf)
{
    const int blk = blockIdx.x;      // (b*512+i)*8 + jc
    const int bi = blk >> 3;         // b*512 + i
    const int jc = blk & 7;          // 64-j chunk
    const int b  = bi >> 9;
    const int t  = threadIdx.x;
    const int r  = t >> 4;           // row slot 0..15
    const int k  = t & 15;           // float4 lane

    const float q0i = q0[bi];
    const f4 pi4 = ((const f4*)P)[bi * 16 + k];
    const f4 vi4 = ((const f4*)Vn)[bi * 16 + k];
    const f4* erow  = (const f4*)(e     + (size_t)bi * NN * 64);
    f4*       enrow = (f4*)      (e_new + (size_t)bi * NN * 64);
    const f4* Prow  = (const f4*)P  + (size_t)b * NN * 16;
    const f4* Vrow  = (const f4*)Vn + (size_t)b * NN * 16;
    const float* q0b = q0 + b * NN;

#pragma unroll
    for (int bb = 0; bb < 2; ++bb) {
        f4 ev[2], pj[2], vj[2];
        float qj[2];
        int jj[2];
#pragma unroll
        for (int u = 0; u < 2; ++u) {
            jj[u] = jc * 64 + (bb * 2 + u) * 16 + r;
            ev[u] = erow[jj[u] * 16 + k];
            pj[u] = Prow[jj[u] * 16 + k];
            vj[u] = Vrow[jj[u] * 16 + k];
            qj[u] = q0b[jj[u]];
        }
#pragma unroll
        for (int u = 0; u < 2; ++u) {
            float s = ev[u].x * (pj[u].x - pi4.x) + ev[u].y * (pj[u].y - pi4.y)
                    + ev[u].z * (pj[u].z - pi4.z) + ev[u].w * (pj[u].w - pi4.w);
            s += __shfl_xor(s, 1);
            s += __shfl_xor(s, 2);
            s += __shfl_xor(s, 4);
            s += __shfl_xor(s, 8);
            const float ai = 1.f / (1.f + expf(-(s * 0.125f + qj[u] - q0i)));
            if (k == 0) AiBuf[(size_t)bi * NN + jj[u]] = ai;
            f4 en;
            en.x = fmaf(ai, vj[u].x - vi4.x, vi4.x);
            en.y = fmaf(ai, vj[u].y - vi4.y, vi4.y);
            en.z = fmaf(ai, vj[u].z - vi4.z, vi4.z);
            en.w = fmaf(ai, vj[u].w - vi4.w, vi4.w);
            __builtin_nontemporal_store(en, enrow + jj[u] * 16 + k);
        }
    }
}

// ---------- edge-to-node (512 thr): softmax over Ai*(u_j-u_i), PV ----------
__global__ __launch_bounds__(512) void node_kernel(
    const float* __restrict__ Qn, const float* __restrict__ VnWke,
    const float* __restrict__ VnWve, const float* __restrict__ bve,
    const float* __restrict__ AiBuf, float* __restrict__ x_new)
{
    const int bi = blockIdx.x;       // b*512 + i
    const int b = bi >> 9, i = bi & 511;
    const int t = threadIdx.x;

    __shared__ float qn[64];
    __shared__ float us[512], as_[512], cs[512];
    __shared__ float red[512];

    if (t < 64) qn[t] = Qn[bi * 64 + t];
    as_[t] = AiBuf[(size_t)bi * NN + t];
    __syncthreads();

    // us[j] = 0.125 * qn . VnWke[b,j]  (4-lane groups, 4 passes)
    {
        const int j4 = t >> 2, l = t & 3;
        const float4* qq = (const float4*)qn;
#pragma unroll
        for (int pass = 0; pass < 4; ++pass) {
            const int j = pass * 128 + j4;
            const float4* wr = (const float4*)(VnWke + (size_t)(b * NN + j) * 64) + l * 4;
            float s = 0.f;
#pragma unroll
            for (int kk = 0; kk < 4; ++kk) {
                const float4 w = wr[kk];
                const float4 qv = qq[l * 4 + kk];
                s += qv.x * w.x + qv.y * w.y + qv.z * w.z + qv.w * w.w;
            }
            s += __shfl_xor(s, 1);
            s += __shfl_xor(s, 2);
            if (l == 0) us[j] = s * 0.125f;
        }
    }
    __syncthreads();

    // softmax over v_j = Ai_j*(u_j - u_i), then PV (512 threads)
    const int lane = t & 63, w = t >> 6;
    const float uii = us[i];
    const float v0 = as_[t] * (us[t] - uii);
    float m = v0;
#pragma unroll
    for (int o = 1; o < 64; o <<= 1) m = fmaxf(m, __shfl_xor(m, o));
    if (lane == 0) red[w] = m;
    __syncthreads();
    float mx = red[0];
#pragma unroll
    for (int z = 1; z < 8; ++z) mx = fmaxf(mx, red[z]);
    const float e0 = expf(v0 - mx);
    float ss = e0;
#pragma unroll
    for (int o = 1; o < 64; o <<= 1) ss += __shfl_xor(ss, o);
    if (lane == 0) red[8 + w] = ss;
    __syncthreads();
    const float inv = 1.f / (red[8] + red[9] + red[10] + red[11]
                           + red[12] + red[13] + red[14] + red[15]);
    const float c0v = e0 * inv * as_[t];
    cs[t] = c0v;
    float gg = c0v;
#pragma unroll
    for (int o = 1; o < 64; o <<= 1) gg += __shfl_xor(gg, o);
    if (lane == 0) red[16 + w] = gg;
    __syncthreads();
    const float g = red[16] + red[17] + red[18] + red[19]
                  + red[20] + red[21] + red[22] + red[23];
    __syncthreads();                     // protect red[] before PV reuse

    const int d = t & 63, q = t >> 6;
    float acc = 0.f;
    const int j0 = q * 64;
    for (int j = j0; j < j0 + 64; ++j)
        acc = fmaf(cs[j], VnWve[(b * NN + j) * 64 + d], acc);
    red[t] = acc;
    __syncthreads();
    if (t < 64) {
        float s8 = 0.f;
#pragma unroll
        for (int z = 0; z < 8; ++z) s8 += red[t + z * 64];
        x_new[bi * 64 + t] = bve[t] + VnWve[bi * 64 + t] * (1.f - g) + s8;
    }
}

extern "C" void kernel_launch(void* const* d_in, const int* in_sizes, int n_in,
                              void* d_out, int out_size, void* d_ws, size_t ws_size,
                              hipStream_t stream) {
    const float* x   = (const float*)d_in[0];
    const float* e   = (const float*)d_in[1];
    const float* Wq1 = (const float*)d_in[2];  const float* bq1 = (const float*)d_in[3];
    const float* Wk1 = (const float*)d_in[4];  const float* bk1 = (const float*)d_in[5];
    const float* Wv1 = (const float*)d_in[6];  const float* bv1 = (const float*)d_in[7];
    const float* Wqe = (const float*)d_in[8];  const float* bqe = (const float*)d_in[9];
    const float* Wkn = (const float*)d_in[10]; const float* bkn = (const float*)d_in[11];
    const float* Wvn = (const float*)d_in[12]; const float* bvn = (const float*)d_in[13];
    const float* Wqn = (const float*)d_in[14]; const float* bqn = (const float*)d_in[15];
    const float* Wke = (const float*)d_in[16]; /* bke cancels in softmax */
    const float* Wve = (const float*)d_in[18]; const float* bve = (const float*)d_in[19];

    float* out = (float*)d_out;
    float* x_new = out;                 // (2,512,64)
    float* e_new = out + 2 * NN * 64;   // (2,512,512,64)

    float* ws = (float*)d_ws;
    const int R = 2 * NN;               // 1024 rows of 64
    float* Q     = ws;                  // R*64 each
    float* K     = Q + R * 64;
    float* V     = K + R * 64;
    float* xhat  = V + R * 64;
    float* Qn    = xhat + R * 64;
    float* Vn    = Qn + R * 64;
    float* P     = Vn + R * 64;
    float* VnWke = P + R * 64;
    float* VnWve = VnWke + R * 64;
    float* q0    = VnWve + R * 64;      // R
    float* M_P   = q0 + R;              // 4096 each
    float* M_ke  = M_P + 4096;
    float* M_ve  = M_ke + 4096;
    float* c_P   = M_ve + 4096;         // 64 each
    float* c_ke  = c_P + 64;
    float* c_ve  = c_ke + 64;
    float* vq0   = c_ve + 64;
    float* s0    = vq0 + 64;            // 1
    float* Ai    = s0 + 64;             // 2*512*512 (aligned region)

    precompute_kernel<<<3, 256, 0, stream>>>(Wkn, bkn, Wvn, bvn, Wqe, bqe, Wke, Wve,
                                             M_P, c_P, M_ke, c_ke, M_ve, c_ve, vq0, s0);
    proj3_tiled<<<32, 256, 0, stream>>>(x, Wq1, bq1, Wk1, bk1, Wv1, bv1, Q, K, V);
    selfattn_kernel<<<R, 512, 0, stream>>>(Q, K, V, xhat);
    affine5_kernel<<<dim3(32, 5), 256, 0, stream>>>(xhat, Wqn, bqn, Wvn, bvn,
                                                    M_P, c_P, M_ke, c_ke, M_ve, c_ve,
                                                    vq0, s0,
                                                    Qn, Vn, P, VnWke, VnWve, q0);
    edge_kernel<<<R * 8, 256, 0, stream>>>(e, P, q0, Vn, e_new, Ai);
    node_kernel<<<R, 512, 0, stream>>>(Qn, VnWke, VnWve, bve, Ai, x_new);
}

// Round 9
// 105.697 us; speedup vs baseline: 1.0572x; 1.0572x over previous
//
#include <hip/hip_runtime.h>
#include <math.h>

// B=2, N=512, D=64, DH=64
#define NN 512

typedef float f4 __attribute__((ext_vector_type(4)));  // native vec for nontemporal builtins

// ---------------- precompute weight products (runs once per launch, 3 blocks) ----------------
__global__ __launch_bounds__(256) void precompute_kernel(
    const float* __restrict__ Wkn, const float* __restrict__ bkn,
    const float* __restrict__ Wvn, const float* __restrict__ bvn,
    const float* __restrict__ Wqe, const float* __restrict__ bqe,
    const float* __restrict__ Wke, const float* __restrict__ Wve,
    float* __restrict__ M_P, float* __restrict__ c_P,
    float* __restrict__ M_ke, float* __restrict__ c_ke,
    float* __restrict__ M_ve, float* __restrict__ c_ve,
    float* __restrict__ vq0, float* __restrict__ s0p)
{
    const int m = blockIdx.x;
    const int t = threadIdx.x;
    __shared__ float As[64 * 65];   // A row-major, padded
    __shared__ float Bs[64 * 65];   // Bs[b][k] = B-operand with dot axis k
    __shared__ float va[64], vb[64];
    const float* A  = (m == 0) ? Wkn : Wvn;
    const float* aV = (m == 0) ? bkn : bvn;
    const float* B  = (m == 0) ? Wqe : (m == 1 ? Wke : Wve);

#pragma unroll
    for (int p = 0; p < 16; ++p) {
        const int idx = p * 256 + t;           // 4096 elements
        const int r = idx >> 6, cc = idx & 63;
        As[r * 65 + cc] = A[idx];
        if (m == 0) Bs[r * 65 + cc] = B[idx];  // Wqe[b][k] already dot-over-k layout
        else        Bs[cc * 65 + r] = B[idx];  // transpose Wke/Wve: Bs[b][k] = B[k][b]
    }
    if (t < 64) { va[t] = aV[t]; vb[t] = bqe[t]; }
    __syncthreads();

    const int b = t & 63, g = t >> 6;          // thread: column b, 16 rows (g*16..)
    float acc[16];
#pragma unroll
    for (int aa = 0; aa < 16; ++aa) acc[aa] = 0.f;
    for (int k = 0; k < 64; ++k) {
        const float bv = Bs[b * 65 + k];       // banks (b+k)%32: conflict-free
#pragma unroll
        for (int aa = 0; aa < 16; ++aa)        // As read is wave-broadcast
            acc[aa] = fmaf(As[(g * 16 + aa) * 65 + k], bv, acc[aa]);
    }
    float* M = (m == 0) ? M_P : (m == 1 ? M_ke : M_ve);
#pragma unroll
    for (int aa = 0; aa < 16; ++aa)
        M[(g * 16 + aa) * 64 + b] = acc[aa];

    if (t < 64) {
        float cb = 0.f;
        for (int k = 0; k < 64; ++k) cb = fmaf(va[k], Bs[t * 65 + k], cb);
        float* C = (m == 0) ? c_P : (m == 1 ? c_ke : c_ve);
        C[t] = cb;
        if (m == 0) {
            float q = 0.f;
            for (int k = 0; k < 64; ++k) q = fmaf(As[t * 65 + k], vb[k], q);
            vq0[t] = q * 0.125f;
        }
    }
    if (m == 0 && t == 0) {
        float s = 0.f;
        for (int k = 0; k < 64; ++k) s += vb[k] * va[k];
        *s0p = s * 0.125f;
    }
}

// ---------------- tiled 3-way projection: 32 rows/block, weights in LDS ----------------
__global__ __launch_bounds__(256) void proj3_tiled(
    const float* __restrict__ in,
    const float* __restrict__ W0, const float* __restrict__ b0,
    const float* __restrict__ W1, const float* __restrict__ b1,
    const float* __restrict__ W2, const float* __restrict__ b2,
    float* __restrict__ o0, float* __restrict__ o1, float* __restrict__ o2)
{
    const int t = threadIdx.x;
    const int rb = blockIdx.x * 32;
    __shared__ float Ws0[4096], Ws1[4096], Ws2[4096];
    __shared__ float xs[2048];
    __shared__ float bs0[64], bs1[64], bs2[64];
#pragma unroll
    for (int p = 0; p < 4; ++p) {
        const int idx = p * 256 + t;
        ((f4*)Ws0)[idx] = ((const f4*)W0)[idx];
        ((f4*)Ws1)[idx] = ((const f4*)W1)[idx];
        ((f4*)Ws2)[idx] = ((const f4*)W2)[idx];
    }
    ((f4*)xs)[t]       = ((const f4*)(in + rb * 64))[t];
    ((f4*)xs)[t + 256] = ((const f4*)(in + rb * 64))[t + 256];
    if (t < 64) { bs0[t] = b0[t]; bs1[t] = b1[t]; bs2[t] = b2[t]; }
    __syncthreads();

    const int d = t & 63, g = t >> 6;          // wave g owns rows g*8..g*8+7
    float a0[8], a1[8], a2[8];
#pragma unroll
    for (int r = 0; r < 8; ++r) { a0[r] = bs0[d]; a1[r] = bs1[d]; a2[r] = bs2[d]; }
    for (int k4 = 0; k4 < 16; ++k4) {
        float w0[4], w1[4], w2[4];
#pragma unroll
        for (int kk = 0; kk < 4; ++kk) {
            w0[kk] = Ws0[(k4 * 4 + kk) * 64 + d];
            w1[kk] = Ws1[(k4 * 4 + kk) * 64 + d];
            w2[kk] = Ws2[(k4 * 4 + kk) * 64 + d];
        }
#pragma unroll
        for (int r = 0; r < 8; ++r) {
            const f4 xv = ((const f4*)xs)[(g * 8 + r) * 16 + k4];  // wave-broadcast b128
            a0[r] = fmaf(xv.x, w0[0], fmaf(xv.y, w0[1], fmaf(xv.z, w0[2], fmaf(xv.w, w0[3], a0[r]))));
            a1[r] = fmaf(xv.x, w1[0], fmaf(xv.y, w1[1], fmaf(xv.z, w1[2], fmaf(xv.w, w1[3], a1[r]))));
            a2[r] = fmaf(xv.x, w2[0], fmaf(xv.y, w2[1], fmaf(xv.z, w2[2], fmaf(xv.w, w2[3], a2[r]))));
        }
    }
#pragma unroll
    for (int r = 0; r < 8; ++r) {
        o0[(rb + g * 8 + r) * 64 + d] = a0[r];
        o1[(rb + g * 8 + r) * 64 + d] = a1[r];
        o2[(rb + g * 8 + r) * 64 + d] = a2[r];
    }
}

// ---------------- fused affine maps of xhat: Qn, Vn, P, VnWke, VnWve, q0 ----------------
__global__ __launch_bounds__(256) void affine5_kernel(
    const float* __restrict__ xhat,
    const float* __restrict__ Wqn, const float* __restrict__ bqn,
    const float* __restrict__ Wvn, const float* __restrict__ bvn,
    const float* __restrict__ M_P, const float* __restrict__ c_P,
    const float* __restrict__ M_ke, const float* __restrict__ c_ke,
    const float* __restrict__ M_ve, const float* __restrict__ c_ve,
    const float* __restrict__ vq0, const float* __restrict__ s0p,
    float* __restrict__ Qn, float* __restrict__ Vn, float* __restrict__ P,
    float* __restrict__ VnWke, float* __restrict__ VnWve, float* __restrict__ q0)
{
    const int t = threadIdx.x;
    const int rb = blockIdx.x * 32;
    const int m = blockIdx.y;
    const float* W; const float* c; float* o;
    if (m == 0)      { W = Wqn;  c = bqn;  o = Qn; }
    else if (m == 1) { W = Wvn;  c = bvn;  o = Vn; }
    else if (m == 2) { W = M_P;  c = c_P;  o = P; }
    else if (m == 3) { W = M_ke; c = c_ke; o = VnWke; }
    else             { W = M_ve; c = c_ve; o = VnWve; }
    __shared__ float Ws[4096], xs[2048], cs[64], vq0s[64];
#pragma unroll
    for (int p = 0; p < 4; ++p) ((f4*)Ws)[p * 256 + t] = ((const f4*)W)[p * 256 + t];
    ((f4*)xs)[t]       = ((const f4*)(xhat + rb * 64))[t];
    ((f4*)xs)[t + 256] = ((const f4*)(xhat + rb * 64))[t + 256];
    if (t < 64) { cs[t] = c[t]; if (m == 0) vq0s[t] = vq0[t]; }
    __syncthreads();

    const int d = t & 63, g = t >> 6;
    float acc[8];
#pragma unroll
    for (int r = 0; r < 8; ++r) acc[r] = cs[d];
    for (int k4 = 0; k4 < 16; ++k4) {
        float w[4];
#pragma unroll
        for (int kk = 0; kk < 4; ++kk) w[kk] = Ws[(k4 * 4 + kk) * 64 + d];
#pragma unroll
        for (int r = 0; r < 8; ++r) {
            const f4 xv = ((const f4*)xs)[(g * 8 + r) * 16 + k4];
            acc[r] = fmaf(xv.x, w[0], fmaf(xv.y, w[1], fmaf(xv.z, w[2], fmaf(xv.w, w[3], acc[r]))));
        }
    }
#pragma unroll
    for (int r = 0; r < 8; ++r) o[(rb + g * 8 + r) * 64 + d] = acc[r];

    if (m == 0) {
        const int row = t >> 3, seg = t & 7;
        float part = 0.f;
#pragma unroll
        for (int kk = 0; kk < 8; ++kk)
            part = fmaf(xs[row * 64 + seg * 8 + kk], vq0s[seg * 8 + kk], part);
        part += __shfl_xor(part, 1);
        part += __shfl_xor(part, 2);
        part += __shfl_xor(part, 4);
        if (seg == 0) q0[rb + row] = part + s0p[0];
    }
}

// ---------------- tiled batched GEMM-T: O[b][r][m] = scale * A[b,r,:].B[b,m,:] ----------------
__global__ __launch_bounds__(256) void gemmT_kernel(
    const float* __restrict__ A, const float* __restrict__ Bm,
    float* __restrict__ O, float scale)
{
    const int tn = blockIdx.x, tm = blockIdx.y, b = blockIdx.z;
    const int t = threadIdx.x;
    __shared__ float As[64 * 65], Bs[64 * 65];
    const float* Ab = A  + ((size_t)b * NN + tn * 64) * 64;
    const float* Bb = Bm + ((size_t)b * NN + tm * 64) * 64;
#pragma unroll
    for (int p = 0; p < 16; ++p) {
        const int idx = p * 256 + t;
        const int r = idx >> 6, k = idx & 63;
        As[r * 65 + k] = Ab[idx];
        Bs[r * 65 + k] = Bb[idx];
    }
    __syncthreads();
    const int m = t & 63, g = t >> 6;
    float acc[16];
#pragma unroll
    for (int a = 0; a < 16; ++a) acc[a] = 0.f;
    for (int k = 0; k < 64; ++k) {
        const float bv = Bs[m * 65 + k];       // (m+k)%32 banks: conflict-free
#pragma unroll
        for (int a = 0; a < 16; ++a)           // As wave-broadcast
            acc[a] = fmaf(As[(g * 16 + a) * 65 + k], bv, acc[a]);
    }
    float* Ob = O + ((size_t)b * NN + tn * 64) * NN + tm * 64;
#pragma unroll
    for (int a = 0; a < 16; ++a)
        Ob[(size_t)(g * 16 + a) * NN + m] = acc[a] * scale;
}

// ---------------- fused row-softmax + PV: xhat = softmax(S) @ V (4 rows/block) ----------------
__global__ __launch_bounds__(256) void smpv_kernel(
    const float* __restrict__ S, const float* __restrict__ V,
    float* __restrict__ xhat)
{
    const int blk = blockIdx.x;              // b*128 + chunk
    const int b = blk >> 7, rb = (blk & 127) * 4;
    const int t = threadIdx.x;
    const int w = t >> 6, l = t & 63;        // wave w owns row rb+w
    __shared__ float pr[4 * 512];
#pragma unroll
    for (int p = 0; p < 8; ++p) {
        const int idx = p * 256 + t;         // 2048
        pr[idx] = S[((size_t)b * NN + rb + (idx >> 9)) * NN + (idx & 511)];
    }
    __syncthreads();
    float* prw = pr + w * 512;
    float v[8];
#pragma unroll
    for (int z = 0; z < 8; ++z) v[z] = prw[l + z * 64];
    float mx = v[0];
#pragma unroll
    for (int z = 1; z < 8; ++z) mx = fmaxf(mx, v[z]);
#pragma unroll
    for (int o = 1; o < 64; o <<= 1) mx = fmaxf(mx, __shfl_xor(mx, o));
    float se = 0.f;
#pragma unroll
    for (int z = 0; z < 8; ++z) { v[z] = expf(v[z] - mx); se += v[z]; prw[l + z * 64] = v[z]; }
#pragma unroll
    for (int o = 1; o < 64; o <<= 1) se += __shfl_xor(se, o);
    const float inv = 1.f / se;
    __syncthreads();

    const float* Vb = V + (size_t)b * NN * 64;
    float ac0 = 0, ac1 = 0, ac2 = 0, ac3 = 0;
    const f4* prw4 = (const f4*)prw;
    for (int k4 = 0; k4 < 128; ++k4) {
        const f4 pv = prw4[k4];              // wave-broadcast b128
        const int k = k4 * 4;
        ac0 = fmaf(pv.x, Vb[(k + 0) * 64 + l], ac0);
        ac1 = fmaf(pv.y, Vb[(k + 1) * 64 + l], ac1);
        ac2 = fmaf(pv.z, Vb[(k + 2) * 64 + l], ac2);
        ac3 = fmaf(pv.w, Vb[(k + 3) * 64 + l], ac3);
    }
    xhat[((size_t)b * NN + rb + w) * 64 + l] = ((ac0 + ac1) + (ac2 + ac3)) * inv;
}

// ---------- pure streaming edge pass: 8192 blocks x 256 thr, no LDS, no barriers ----------
__global__ __launch_bounds__(256) void edge_kernel(
    const float* __restrict__ e, const float* __restrict__ P,
    const float* __restrict__ q0, const float* __restrict__ Vn,
    float* __restrict__ e_new, float* __restrict__ AiBuf)
{
    const int blk = blockIdx.x;      // (b*512+i)*8 + jc
    const int bi = blk >> 3;         // b*512 + i
    const int jc = blk & 7;          // 64-j chunk
    const int b  = bi >> 9;
    const int t  = threadIdx.x;
    const int r  = t >> 4;           // row slot 0..15
    const int k  = t & 15;           // float4 lane

    const float q0i = q0[bi];
    const f4 pi4 = ((const f4*)P)[bi * 16 + k];
    const f4 vi4 = ((const f4*)Vn)[bi * 16 + k];
    const f4* erow  = (const f4*)(e     + (size_t)bi * NN * 64);
    f4*       enrow = (f4*)      (e_new + (size_t)bi * NN * 64);
    const f4* Prow  = (const f4*)P  + (size_t)b * NN * 16;
    const f4* Vrow  = (const f4*)Vn + (size_t)b * NN * 16;
    const float* q0b = q0 + b * NN;

#pragma unroll
    for (int bb = 0; bb < 2; ++bb) {
        f4 ev[2], pj[2], vj[2];
        float qj[2];
        int jj[2];
#pragma unroll
        for (int u = 0; u < 2; ++u) {
            jj[u] = jc * 64 + (bb * 2 + u) * 16 + r;
            ev[u] = erow[jj[u] * 16 + k];
            pj[u] = Prow[jj[u] * 16 + k];
            vj[u] = Vrow[jj[u] * 16 + k];
            qj[u] = q0b[jj[u]];
        }
#pragma unroll
        for (int u = 0; u < 2; ++u) {
            float s = ev[u].x * (pj[u].x - pi4.x) + ev[u].y * (pj[u].y - pi4.y)
                    + ev[u].z * (pj[u].z - pi4.z) + ev[u].w * (pj[u].w - pi4.w);
            s += __shfl_xor(s, 1);
            s += __shfl_xor(s, 2);
            s += __shfl_xor(s, 4);
            s += __shfl_xor(s, 8);
            const float ai = 1.f / (1.f + expf(-(s * 0.125f + qj[u] - q0i)));
            if (k == 0) AiBuf[(size_t)bi * NN + jj[u]] = ai;
            f4 en;
            en.x = fmaf(ai, vj[u].x - vi4.x, vi4.x);
            en.y = fmaf(ai, vj[u].y - vi4.y, vi4.y);
            en.z = fmaf(ai, vj[u].z - vi4.z, vi4.z);
            en.w = fmaf(ai, vj[u].w - vi4.w, vi4.w);
            __builtin_nontemporal_store(en, enrow + jj[u] * 16 + k);
        }
    }
}

// ---------- fused coeff-softmax + PV: x_new (4 rows/block) ----------
__global__ __launch_bounds__(256) void coeffpv_kernel(
    const float* __restrict__ U, const float* __restrict__ Ai,
    const float* __restrict__ VnWve, const float* __restrict__ bve,
    float* __restrict__ x_new)
{
    const int blk = blockIdx.x;              // b*128 + chunk
    const int b = blk >> 7, rb = (blk & 127) * 4;
    const int t = threadIdx.x;
    const int w = t >> 6, l = t & 63;        // wave w owns row i = rb+w
    __shared__ float uu[4 * 512];
    __shared__ float aa[4 * 512];
#pragma unroll
    for (int p = 0; p < 8; ++p) {
        const int idx = p * 256 + t;
        const size_t src = ((size_t)b * NN + rb + (idx >> 9)) * NN + (idx & 511);
        uu[idx] = U[src];
        aa[idx] = Ai[src];
    }
    __syncthreads();
    float* uw = uu + w * 512;
    const float* aw = aa + w * 512;
    const float uii = uw[rb + w];            // U[i][i], wave-broadcast
    float v[8], av[8];
#pragma unroll
    for (int z = 0; z < 8; ++z) {
        av[z] = aw[l + z * 64];
        v[z]  = av[z] * (uw[l + z * 64] - uii);
    }
    float mx = v[0];
#pragma unroll
    for (int z = 1; z < 8; ++z) mx = fmaxf(mx, v[z]);
#pragma unroll
    for (int o = 1; o < 64; o <<= 1) mx = fmaxf(mx, __shfl_xor(mx, o));
    float se = 0.f, sea = 0.f;
#pragma unroll
    for (int z = 0; z < 8; ++z) {
        const float e0 = expf(v[z] - mx);
        const float cw = e0 * av[z];
        se += e0; sea += cw;
        uw[l + z * 64] = cw;                 // overwrite u-row with unnorm coeffs
    }
#pragma unroll
    for (int o = 1; o < 64; o <<= 1) { se += __shfl_xor(se, o); sea += __shfl_xor(sea, o); }
    const float inv = 1.f / se;
    const float g = sea * inv;
    __syncthreads();

    const float* Wb = VnWve + (size_t)b * NN * 64;
    float ac0 = 0, ac1 = 0, ac2 = 0, ac3 = 0;
    const f4* cw4 = (const f4*)uw;
    for (int k4 = 0; k4 < 128; ++k4) {
        const f4 pv = cw4[k4];
        const int k = k4 * 4;
        ac0 = fmaf(pv.x, Wb[(k + 0) * 64 + l], ac0);
        ac1 = fmaf(pv.y, Wb[(k + 1) * 64 + l], ac1);
        ac2 = fmaf(pv.z, Wb[(k + 2) * 64 + l], ac2);
        ac3 = fmaf(pv.w, Wb[(k + 3) * 64 + l], ac3);
    }
    const int bi = b * NN + rb + w;
    x_new[(size_t)bi * 64 + l] = bve[l] + VnWve[(size_t)bi * 64 + l] * (1.f - g)
                               + ((ac0 + ac1) + (ac2 + ac3)) * inv;
}

extern "C" void kernel_launch(void* const* d_in, const int* in_sizes, int n_in,
                              void* d_out, int out_size, void* d_ws, size_t ws_size,
                              hipStream_t stream) {
    const float* x   = (const float*)d_in[0];
    const float* e   = (const float*)d_in[1];
    const float* Wq1 = (const float*)d_in[2];  const float* bq1 = (const float*)d_in[3];
    const float* Wk1 = (const float*)d_in[4];  const float* bk1 = (const float*)d_in[5];
    const float* Wv1 = (const float*)d_in[6];  const float* bv1 = (const float*)d_in[7];
    const float* Wqe = (const float*)d_in[8];  const float* bqe = (const float*)d_in[9];
    const float* Wkn = (const float*)d_in[10]; const float* bkn = (const float*)d_in[11];
    const float* Wvn = (const float*)d_in[12]; const float* bvn = (const float*)d_in[13];
    const float* Wqn = (const float*)d_in[14]; const float* bqn = (const float*)d_in[15];
    const float* Wke = (const float*)d_in[16]; /* bke cancels in softmax */
    const float* Wve = (const float*)d_in[18]; const float* bve = (const float*)d_in[19];

    float* out = (float*)d_out;
    float* x_new = out;                 // (2,512,64)
    float* e_new = out + 2 * NN * 64;   // (2,512,512,64)

    float* ws = (float*)d_ws;
    const int R = 2 * NN;               // 1024 rows of 64
    float* Q     = ws;                  // R*64 each
    float* K     = Q + R * 64;
    float* V     = K + R * 64;
    float* xhat  = V + R * 64;
    float* Qn    = xhat + R * 64;
    float* Vn    = Qn + R * 64;
    float* P     = Vn + R * 64;
    float* VnWke = P + R * 64;
    float* VnWve = VnWke + R * 64;
    float* q0    = VnWve + R * 64;      // R
    float* M_P   = q0 + R;              // 4096 each
    float* M_ke  = M_P + 4096;
    float* M_ve  = M_ke + 4096;
    float* c_P   = M_ve + 4096;         // 64 each
    float* c_ke  = c_P + 64;
    float* c_ve  = c_ke + 64;
    float* vq0   = c_ve + 64;
    float* s0    = vq0 + 64;            // 64 (pad)
    float* Smat  = s0 + 64;             // 2*512*512
    float* Umat  = Smat + (size_t)R * NN;
    float* Ai    = Umat + (size_t)R * NN;

    precompute_kernel<<<3, 256, 0, stream>>>(Wkn, bkn, Wvn, bvn, Wqe, bqe, Wke, Wve,
                                             M_P, c_P, M_ke, c_ke, M_ve, c_ve, vq0, s0);
    proj3_tiled<<<32, 256, 0, stream>>>(x, Wq1, bq1, Wk1, bk1, Wv1, bv1, Q, K, V);
    gemmT_kernel<<<dim3(8, 8, 2), 256, 0, stream>>>(Q, K, Smat, 0.125f);
    smpv_kernel<<<256, 256, 0, stream>>>(Smat, V, xhat);
    affine5_kernel<<<dim3(32, 5), 256, 0, stream>>>(xhat, Wqn, bqn, Wvn, bvn,
                                                    M_P, c_P, M_ke, c_ke, M_ve, c_ve,
                                                    vq0, s0,
                                                    Qn, Vn, P, VnWke, VnWve, q0);
    gemmT_kernel<<<dim3(8, 8, 2), 256, 0, stream>>>(Qn, VnWke, Umat, 0.125f);
    edge_kernel<<<R * 8, 256, 0, stream>>>(e, P, q0, Vn, e_new, Ai);
    coeffpv_kernel<<<256, 256, 0, stream>>>(Umat, Ai, VnWve, bve, x_new);
}

// Round 10
// 97.908 us; speedup vs baseline: 1.1413x; 1.0796x over previous
//
#include <hip/hip_runtime.h>
#include <math.h>

// B=2, N=512, D=64, DH=64
#define NN 512

typedef float f4 __attribute__((ext_vector_type(4)));  // native vec for nontemporal builtins

// ---------------- prep: blocks 0-2 = weight-product precompute; blocks 3-34 = proj3 ----------------
// precompute m=0: M_P = Wkn@Wqe^T ; c_P = bkn@Wqe^T ; vq0 = 0.125*(Wkn@bqe) ; s0 = 0.125*(bqe.bkn)
//            m=1: M_ke = Wvn@Wke  ; c_ke = bvn@Wke
//            m=2: M_ve = Wvn@Wve  ; c_ve = bvn@Wve
// proj3: Q,K,V = x@W{q1,k1,v1} + b
__global__ __launch_bounds__(256) void prep_kernel(
    const float* __restrict__ x,
    const float* __restrict__ Wq1, const float* __restrict__ bq1,
    const float* __restrict__ Wk1, const float* __restrict__ bk1,
    const float* __restrict__ Wv1, const float* __restrict__ bv1,
    const float* __restrict__ Wkn, const float* __restrict__ bkn,
    const float* __restrict__ Wvn, const float* __restrict__ bvn,
    const float* __restrict__ Wqe, const float* __restrict__ bqe,
    const float* __restrict__ Wke, const float* __restrict__ Wve,
    float* __restrict__ Q, float* __restrict__ K, float* __restrict__ V,
    float* __restrict__ M_P, float* __restrict__ c_P,
    float* __restrict__ M_ke, float* __restrict__ c_ke,
    float* __restrict__ M_ve, float* __restrict__ c_ve,
    float* __restrict__ vq0, float* __restrict__ s0p)
{
    __shared__ float sh[14528];
    const int t = threadIdx.x;

    if (blockIdx.x < 3) {
        const int m = blockIdx.x;
        float* As = sh;                 // 64*65
        float* Bs = sh + 4160;          // 64*65
        float* va = sh + 8320;          // 64
        float* vb = sh + 8384;          // 64
        const float* A  = (m == 0) ? Wkn : Wvn;
        const float* aV = (m == 0) ? bkn : bvn;
        const float* B  = (m == 0) ? Wqe : (m == 1 ? Wke : Wve);
#pragma unroll
        for (int p = 0; p < 16; ++p) {
            const int idx = p * 256 + t;
            const int r = idx >> 6, cc = idx & 63;
            As[r * 65 + cc] = A[idx];
            if (m == 0) Bs[r * 65 + cc] = B[idx];
            else        Bs[cc * 65 + r] = B[idx];
        }
        if (t < 64) { va[t] = aV[t]; vb[t] = bqe[t]; }
        __syncthreads();

        const int b = t & 63, g = t >> 6;
        float acc[16];
#pragma unroll
        for (int aa = 0; aa < 16; ++aa) acc[aa] = 0.f;
        for (int k = 0; k < 64; ++k) {
            const float bv = Bs[b * 65 + k];
#pragma unroll
            for (int aa = 0; aa < 16; ++aa)
                acc[aa] = fmaf(As[(g * 16 + aa) * 65 + k], bv, acc[aa]);
        }
        float* M = (m == 0) ? M_P : (m == 1 ? M_ke : M_ve);
#pragma unroll
        for (int aa = 0; aa < 16; ++aa)
            M[(g * 16 + aa) * 64 + b] = acc[aa];

        if (t < 64) {
            float cb = 0.f;
            for (int k = 0; k < 64; ++k) cb = fmaf(va[k], Bs[t * 65 + k], cb);
            float* C = (m == 0) ? c_P : (m == 1 ? c_ke : c_ve);
            C[t] = cb;
            if (m == 0) {
                float q = 0.f;
                for (int k = 0; k < 64; ++k) q = fmaf(As[t * 65 + k], vb[k], q);
                vq0[t] = q * 0.125f;
            }
        }
        if (m == 0 && t == 0) {
            float s = 0.f;
            for (int k = 0; k < 64; ++k) s += vb[k] * va[k];
            *s0p = s * 0.125f;
        }
    } else {
        const int rb = (blockIdx.x - 3) * 32;
        float* Ws0 = sh;                // 4096 each
        float* Ws1 = sh + 4096;
        float* Ws2 = sh + 8192;
        float* xs  = sh + 12288;        // 2048
        float* bs0 = sh + 14336;        // 64 each
        float* bs1 = sh + 14400;
        float* bs2 = sh + 14464;
#pragma unroll
        for (int p = 0; p < 4; ++p) {
            const int idx = p * 256 + t;
            ((f4*)Ws0)[idx] = ((const f4*)Wq1)[idx];
            ((f4*)Ws1)[idx] = ((const f4*)Wk1)[idx];
            ((f4*)Ws2)[idx] = ((const f4*)Wv1)[idx];
        }
        ((f4*)xs)[t]       = ((const f4*)(x + rb * 64))[t];
        ((f4*)xs)[t + 256] = ((const f4*)(x + rb * 64))[t + 256];
        if (t < 64) { bs0[t] = bq1[t]; bs1[t] = bk1[t]; bs2[t] = bv1[t]; }
        __syncthreads();

        const int d = t & 63, g = t >> 6;
        float a0[8], a1[8], a2[8];
#pragma unroll
        for (int r = 0; r < 8; ++r) { a0[r] = bs0[d]; a1[r] = bs1[d]; a2[r] = bs2[d]; }
        for (int k4 = 0; k4 < 16; ++k4) {
            float w0[4], w1[4], w2[4];
#pragma unroll
            for (int kk = 0; kk < 4; ++kk) {
                w0[kk] = Ws0[(k4 * 4 + kk) * 64 + d];
                w1[kk] = Ws1[(k4 * 4 + kk) * 64 + d];
                w2[kk] = Ws2[(k4 * 4 + kk) * 64 + d];
            }
#pragma unroll
            for (int r = 0; r < 8; ++r) {
                const f4 xv = ((const f4*)xs)[(g * 8 + r) * 16 + k4];
                a0[r] = fmaf(xv.x, w0[0], fmaf(xv.y, w0[1], fmaf(xv.z, w0[2], fmaf(xv.w, w0[3], a0[r]))));
                a1[r] = fmaf(xv.x, w1[0], fmaf(xv.y, w1[1], fmaf(xv.z, w1[2], fmaf(xv.w, w1[3], a1[r]))));
                a2[r] = fmaf(xv.x, w2[0], fmaf(xv.y, w2[1], fmaf(xv.z, w2[2], fmaf(xv.w, w2[3], a2[r]))));
            }
        }
#pragma unroll
        for (int r = 0; r < 8; ++r) {
            Q[(rb + g * 8 + r) * 64 + d] = a0[r];
            K[(rb + g * 8 + r) * 64 + d] = a1[r];
            V[(rb + g * 8 + r) * 64 + d] = a2[r];
        }
    }
}

// ---------- node-to-node self attention (512 thr): x_hat = softmax(QK^T/8) @ V ----------
__global__ __launch_bounds__(512) void selfattn_kernel(
    const float* __restrict__ Q, const float* __restrict__ K,
    const float* __restrict__ V, float* __restrict__ xhat)
{
    const int row = blockIdx.x;            // b*512 + n
    const int b = row >> 9;
    const int t = threadIdx.x;
    __shared__ float qr[64];
    __shared__ float p[512];
    __shared__ float red[512];
    if (t < 64) qr[t] = Q[row * 64 + t];
    __syncthreads();

    {
        const int m = t;
        const f4* kr = (const f4*)(K + (size_t)(b * NN + m) * 64);
        const f4* qq = (const f4*)qr;
        float sp[4] = {0.f, 0.f, 0.f, 0.f};
#pragma unroll
        for (int u = 0; u < 16; ++u) {
            const f4 w = kr[u];
            const f4 qv = qq[u];
            sp[u & 3] += qv.x * w.x + qv.y * w.y + qv.z * w.z + qv.w * w.w;
        }
        p[m] = ((sp[0] + sp[1]) + (sp[2] + sp[3])) * 0.125f;
    }
    __syncthreads();

    const int lane = t & 63, w = t >> 6;
    const float v0 = p[t];
    float m = v0;
#pragma unroll
    for (int o = 1; o < 64; o <<= 1) m = fmaxf(m, __shfl_xor(m, o));
    if (lane == 0) red[w] = m;
    __syncthreads();
    float mx = red[0];
#pragma unroll
    for (int z = 1; z < 8; ++z) mx = fmaxf(mx, red[z]);
    const float e0 = expf(v0 - mx);
    float ss = e0;
#pragma unroll
    for (int o = 1; o < 64; o <<= 1) ss += __shfl_xor(ss, o);
    if (lane == 0) red[8 + w] = ss;
    __syncthreads();
    const float inv = 1.f / (red[8] + red[9] + red[10] + red[11]
                           + red[12] + red[13] + red[14] + red[15]);
    p[t] = e0;
    __syncthreads();

    const int d = t & 63, q = t >> 6;
    float acc = 0.f;
    const int j0 = q * 64;
    for (int j = j0; j < j0 + 64; ++j)
        acc = fmaf(p[j], V[(b * NN + j) * 64 + d], acc);
    red[t] = acc;
    __syncthreads();
    if (t < 64) {
        float s8 = 0.f;
#pragma unroll
        for (int z = 0; z < 8; ++z) s8 += red[t + z * 64];
        xhat[row * 64 + t] = s8 * inv;
    }
}

// ---------------- fused affine maps of xhat: Qn, Vn, P, VnWke, VnWve, q0 ----------------
__global__ __launch_bounds__(256) void affine5_kernel(
    const float* __restrict__ xhat,
    const float* __restrict__ Wqn, const float* __restrict__ bqn,
    const float* __restrict__ Wvn, const float* __restrict__ bvn,
    const float* __restrict__ M_P, const float* __restrict__ c_P,
    const float* __restrict__ M_ke, const float* __restrict__ c_ke,
    const float* __restrict__ M_ve, const float* __restrict__ c_ve,
    const float* __restrict__ vq0, const float* __restrict__ s0p,
    float* __restrict__ Qn, float* __restrict__ Vn, float* __restrict__ P,
    float* __restrict__ VnWke, float* __restrict__ VnWve, float* __restrict__ q0)
{
    const int t = threadIdx.x;
    const int rb = blockIdx.x * 32;
    const int m = blockIdx.y;
    const float* W; const float* c; float* o;
    if (m == 0)      { W = Wqn;  c = bqn;  o = Qn; }
    else if (m == 1) { W = Wvn;  c = bvn;  o = Vn; }
    else if (m == 2) { W = M_P;  c = c_P;  o = P; }
    else if (m == 3) { W = M_ke; c = c_ke; o = VnWke; }
    else             { W = M_ve; c = c_ve; o = VnWve; }
    __shared__ float Ws[4096], xs[2048], cs[64], vq0s[64];
#pragma unroll
    for (int p = 0; p < 4; ++p) ((f4*)Ws)[p * 256 + t] = ((const f4*)W)[p * 256 + t];
    ((f4*)xs)[t]       = ((const f4*)(xhat + rb * 64))[t];
    ((f4*)xs)[t + 256] = ((const f4*)(xhat + rb * 64))[t + 256];
    if (t < 64) { cs[t] = c[t]; if (m == 0) vq0s[t] = vq0[t]; }
    __syncthreads();

    const int d = t & 63, g = t >> 6;
    float acc[8];
#pragma unroll
    for (int r = 0; r < 8; ++r) acc[r] = cs[d];
    for (int k4 = 0; k4 < 16; ++k4) {
        float w[4];
#pragma unroll
        for (int kk = 0; kk < 4; ++kk) w[kk] = Ws[(k4 * 4 + kk) * 64 + d];
#pragma unroll
        for (int r = 0; r < 8; ++r) {
            const f4 xv = ((const f4*)xs)[(g * 8 + r) * 16 + k4];
            acc[r] = fmaf(xv.x, w[0], fmaf(xv.y, w[1], fmaf(xv.z, w[2], fmaf(xv.w, w[3], acc[r]))));
        }
    }
#pragma unroll
    for (int r = 0; r < 8; ++r) o[(rb + g * 8 + r) * 64 + d] = acc[r];

    if (m == 0) {
        const int row = t >> 3, seg = t & 7;
        float part = 0.f;
#pragma unroll
        for (int kk = 0; kk < 8; ++kk)
            part = fmaf(xs[row * 64 + seg * 8 + kk], vq0s[seg * 8 + kk], part);
        part += __shfl_xor(part, 1);
        part += __shfl_xor(part, 2);
        part += __shfl_xor(part, 4);
        if (seg == 0) q0[rb + row] = part + s0p[0];
    }
}

// ---------- fused edge stream + edge-to-node (256 thr, R4-best form + q0 in LDS) ----------
__global__ __launch_bounds__(256) void edgenode_kernel(
    const float* __restrict__ e, const float* __restrict__ P,
    const float* __restrict__ q0, const float* __restrict__ Vn,
    const float* __restrict__ Qn, const float* __restrict__ VnWke,
    const float* __restrict__ VnWve, const float* __restrict__ bve,
    float* __restrict__ e_new, float* __restrict__ x_new)
{
    const int bi = blockIdx.x;       // b*512 + i
    const int b = bi >> 9, i = bi & 511;
    const int t = threadIdx.x;
    const int r = t >> 4;            // 16 rows (j's) per chunk
    const int k = t & 15;            // float4 lane within row

    __shared__ float qn[64], pis[64], vis[64];
    __shared__ float as_[512], us[512], cs[512], q0s[512];
    __shared__ float red[256];

    if (t < 64) {
        qn[t]  = Qn[bi * 64 + t];
        pis[t] = P[bi * 64 + t];
        vis[t] = Vn[bi * 64 + t];
    }
    q0s[t]       = q0[b * NN + t];
    q0s[t + 256] = q0[b * NN + t + 256];
    __syncthreads();
    const float q0i = q0s[i];
    const float4 pi4 = ((const float4*)pis)[k];
    const float4 vi4 = ((const float4*)vis)[k];
    const float4 qn4 = ((const float4*)qn)[k];

    const f4* erow  = (const f4*)(e     + (size_t)bi * NN * 64);
    f4*       enrow = (f4*)      (e_new + (size_t)bi * NN * 64);

    // phase 1: stream e -> e_new, produce as_[j] (=Ai) and us[j] (=Qn.VnWke_j/8)
    for (int c0 = 0; c0 < 32; ++c0) {
        const int j  = c0 * 16 + r;
        const int bj = b * NN + j;
        const f4 ev = erow[j * 16 + k];
        const float4 pj = ((const float4*)P)[bj * 16 + k];
        const float4 wj = ((const float4*)VnWke)[bj * 16 + k];
        float s = ev.x * (pj.x - pi4.x) + ev.y * (pj.y - pi4.y)
                + ev.z * (pj.z - pi4.z) + ev.w * (pj.w - pi4.w);
        float uu = qn4.x * wj.x + qn4.y * wj.y + qn4.z * wj.z + qn4.w * wj.w;
        s  += __shfl_xor(s, 1);  uu += __shfl_xor(uu, 1);
        s  += __shfl_xor(s, 2);  uu += __shfl_xor(uu, 2);
        s  += __shfl_xor(s, 4);  uu += __shfl_xor(uu, 4);
        s  += __shfl_xor(s, 8);  uu += __shfl_xor(uu, 8);
        const float ai = 1.f / (1.f + expf(-(s * 0.125f + q0s[j] - q0i)));
        const float4 vj = ((const float4*)Vn)[bj * 16 + k];
        f4 en;
        en.x = fmaf(ai, vj.x - vi4.x, vi4.x);
        en.y = fmaf(ai, vj.y - vi4.y, vi4.y);
        en.z = fmaf(ai, vj.z - vi4.z, vi4.z);
        en.w = fmaf(ai, vj.w - vi4.w, vi4.w);
        __builtin_nontemporal_store(en, enrow + j * 16 + k);
        if (k == 0) { as_[j] = ai; us[j] = uu * 0.125f; }
    }
    __syncthreads();

    // phase 2: row softmax over v_j = Ai_j*(u_j - u_i), then PV (256 threads)
    const int lane = t & 63, w = t >> 6;
    const float uii = us[i];
    const float v0 = as_[t] * (us[t] - uii);
    const float v1 = as_[t + 256] * (us[t + 256] - uii);
    float m = fmaxf(v0, v1);
#pragma unroll
    for (int o = 1; o < 64; o <<= 1) m = fmaxf(m, __shfl_xor(m, o));
    if (lane == 0) red[w] = m;
    __syncthreads();
    const float mx = fmaxf(fmaxf(red[0], red[1]), fmaxf(red[2], red[3]));
    const float e0 = expf(v0 - mx), e1 = expf(v1 - mx);
    float ss = e0 + e1;
#pragma unroll
    for (int o = 1; o < 64; o <<= 1) ss += __shfl_xor(ss, o);
    if (lane == 0) red[4 + w] = ss;
    __syncthreads();
    const float inv = 1.f / (red[4] + red[5] + red[6] + red[7]);
    const float c0v = e0 * inv * as_[t];
    const float c1v = e1 * inv * as_[t + 256];
    cs[t] = c0v; cs[t + 256] = c1v;
    float gg = c0v + c1v;
#pragma unroll
    for (int o = 1; o < 64; o <<= 1) gg += __shfl_xor(gg, o);
    if (lane == 0) red[8 + w] = gg;
    __syncthreads();
    const float g = red[8] + red[9] + red[10] + red[11];
    __syncthreads();                     // protect red[] before PV reuse

    const int d = t & 63, q = t >> 6;
    float acc = 0.f;
    const int j0 = q * 128;
    for (int j = j0; j < j0 + 128; ++j)
        acc = fmaf(cs[j], VnWve[(b * NN + j) * 64 + d], acc);
    red[t] = acc;
    __syncthreads();
    if (t < 64) {
        const float s4 = red[t] + red[t + 64] + red[t + 128] + red[t + 192];
        x_new[bi * 64 + t] = bve[t] + VnWve[bi * 64 + t] * (1.f - g) + s4;
    }
}

extern "C" void kernel_launch(void* const* d_in, const int* in_sizes, int n_in,
                              void* d_out, int out_size, void* d_ws, size_t ws_size,
                              hipStream_t stream) {
    const float* x   = (const float*)d_in[0];
    const float* e   = (const float*)d_in[1];
    const float* Wq1 = (const float*)d_in[2];  const float* bq1 = (const float*)d_in[3];
    const float* Wk1 = (const float*)d_in[4];  const float* bk1 = (const float*)d_in[5];
    const float* Wv1 = (const float*)d_in[6];  const float* bv1 = (const float*)d_in[7];
    const float* Wqe = (const float*)d_in[8];  const float* bqe = (const float*)d_in[9];
    const float* Wkn = (const float*)d_in[10]; const float* bkn = (const float*)d_in[11];
    const float* Wvn = (const float*)d_in[12]; const float* bvn = (const float*)d_in[13];
    const float* Wqn = (const float*)d_in[14]; const float* bqn = (const float*)d_in[15];
    const float* Wke = (const float*)d_in[16]; /* bke cancels in softmax */
    const float* Wve = (const float*)d_in[18]; const float* bve = (const float*)d_in[19];

    float* out = (float*)d_out;
    float* x_new = out;                 // (2,512,64)
    float* e_new = out + 2 * NN * 64;   // (2,512,512,64)

    float* ws = (float*)d_ws;
    const int R = 2 * NN;               // 1024 rows of 64
    float* Q     = ws;                  // R*64 each
    float* K     = Q + R * 64;
    float* V     = K + R * 64;
    float* xhat  = V + R * 64;
    float* Qn    = xhat + R * 64;
    float* Vn    = Qn + R * 64;
    float* P     = Vn + R * 64;
    float* VnWke = P + R * 64;
    float* VnWve = VnWke + R * 64;
    float* q0    = VnWve + R * 64;      // R
    float* M_P   = q0 + R;              // 4096 each
    float* M_ke  = M_P + 4096;
    float* M_ve  = M_ke + 4096;
    float* c_P   = M_ve + 4096;         // 64 each
    float* c_ke  = c_P + 64;
    float* c_ve  = c_ke + 64;
    float* vq0   = c_ve + 64;
    float* s0    = vq0 + 64;            // 1

    prep_kernel<<<35, 256, 0, stream>>>(x, Wq1, bq1, Wk1, bk1, Wv1, bv1,
                                        Wkn, bkn, Wvn, bvn, Wqe, bqe, Wke, Wve,
                                        Q, K, V,
                                        M_P, c_P, M_ke, c_ke, M_ve, c_ve, vq0, s0);
    selfattn_kernel<<<R, 512, 0, stream>>>(Q, K, V, xhat);
    affine5_kernel<<<dim3(32, 5), 256, 0, stream>>>(xhat, Wqn, bqn, Wvn, bvn,
                                                    M_P, c_P, M_ke, c_ke, M_ve, c_ve,
                                                    vq0, s0,
                                                    Qn, Vn, P, VnWke, VnWve, q0);
    edgenode_kernel<<<R, 256, 0, stream>>>(e, P, q0, Vn, Qn, VnWke, VnWve, bve,
                                           e_new, x_new);
}

// Round 11
// 95.112 us; speedup vs baseline: 1.1749x; 1.0294x over previous
//
#include <hip/hip_runtime.h>
#include <math.h>

// B=2, N=512, D=64, DH=64
#define NN 512
#define RR 1024   // 2*NN rows

typedef float f4 __attribute__((ext_vector_type(4)));

// ---------------- prep: blocks 0-2 = weight-product precompute; blocks 3-34 = proj3 ----------------
__global__ __launch_bounds__(256) void prep_kernel(
    const float* __restrict__ x,
    const float* __restrict__ Wq1, const float* __restrict__ bq1,
    const float* __restrict__ Wk1, const float* __restrict__ bk1,
    const float* __restrict__ Wv1, const float* __restrict__ bv1,
    const float* __restrict__ Wkn, const float* __restrict__ bkn,
    const float* __restrict__ Wvn, const float* __restrict__ bvn,
    const float* __restrict__ Wqe, const float* __restrict__ bqe,
    const float* __restrict__ Wke, const float* __restrict__ Wve,
    float* __restrict__ Q, float* __restrict__ K, float* __restrict__ V,
    float* __restrict__ M_P, float* __restrict__ c_P,
    float* __restrict__ M_ke, float* __restrict__ c_ke,
    float* __restrict__ M_ve, float* __restrict__ c_ve,
    float* __restrict__ vq0, float* __restrict__ s0p)
{
    __shared__ float sh[14528];
    const int t = threadIdx.x;

    if (blockIdx.x < 3) {
        const int m = blockIdx.x;
        float* As = sh;
        float* Bs = sh + 4160;
        float* va = sh + 8320;
        float* vb = sh + 8384;
        const float* A  = (m == 0) ? Wkn : Wvn;
        const float* aV = (m == 0) ? bkn : bvn;
        const float* B  = (m == 0) ? Wqe : (m == 1 ? Wke : Wve);
#pragma unroll
        for (int p = 0; p < 16; ++p) {
            const int idx = p * 256 + t;
            const int r = idx >> 6, cc = idx & 63;
            As[r * 65 + cc] = A[idx];
            if (m == 0) Bs[r * 65 + cc] = B[idx];
            else        Bs[cc * 65 + r] = B[idx];
        }
        if (t < 64) { va[t] = aV[t]; vb[t] = bqe[t]; }
        __syncthreads();

        const int b = t & 63, g = t >> 6;
        float acc[16];
#pragma unroll
        for (int aa = 0; aa < 16; ++aa) acc[aa] = 0.f;
        for (int k = 0; k < 64; ++k) {
            const float bv = Bs[b * 65 + k];
#pragma unroll
            for (int aa = 0; aa < 16; ++aa)
                acc[aa] = fmaf(As[(g * 16 + aa) * 65 + k], bv, acc[aa]);
        }
        float* M = (m == 0) ? M_P : (m == 1 ? M_ke : M_ve);
#pragma unroll
        for (int aa = 0; aa < 16; ++aa)
            M[(g * 16 + aa) * 64 + b] = acc[aa];

        if (t < 64) {
            float cb = 0.f;
            for (int k = 0; k < 64; ++k) cb = fmaf(va[k], Bs[t * 65 + k], cb);
            float* C = (m == 0) ? c_P : (m == 1 ? c_ke : c_ve);
            C[t] = cb;
            if (m == 0) {
                float q = 0.f;
                for (int k = 0; k < 64; ++k) q = fmaf(As[t * 65 + k], vb[k], q);
                vq0[t] = q * 0.125f;
            }
        }
        if (m == 0 && t == 0) {
            float s = 0.f;
            for (int k = 0; k < 64; ++k) s += vb[k] * va[k];
            *s0p = s * 0.125f;
        }
    } else {
        const int rb = (blockIdx.x - 3) * 32;
        float* Ws0 = sh;
        float* Ws1 = sh + 4096;
        float* Ws2 = sh + 8192;
        float* xs  = sh + 12288;
        float* bs0 = sh + 14336;
        float* bs1 = sh + 14400;
        float* bs2 = sh + 14464;
#pragma unroll
        for (int p = 0; p < 4; ++p) {
            const int idx = p * 256 + t;
            ((f4*)Ws0)[idx] = ((const f4*)Wq1)[idx];
            ((f4*)Ws1)[idx] = ((const f4*)Wk1)[idx];
            ((f4*)Ws2)[idx] = ((const f4*)Wv1)[idx];
        }
        ((f4*)xs)[t]       = ((const f4*)(x + rb * 64))[t];
        ((f4*)xs)[t + 256] = ((const f4*)(x + rb * 64))[t + 256];
        if (t < 64) { bs0[t] = bq1[t]; bs1[t] = bk1[t]; bs2[t] = bv1[t]; }
        __syncthreads();

        const int d = t & 63, g = t >> 6;
        float a0[8], a1[8], a2[8];
#pragma unroll
        for (int r = 0; r < 8; ++r) { a0[r] = bs0[d]; a1[r] = bs1[d]; a2[r] = bs2[d]; }
        for (int k4 = 0; k4 < 16; ++k4) {
            float w0[4], w1[4], w2[4];
#pragma unroll
            for (int kk = 0; kk < 4; ++kk) {
                w0[kk] = Ws0[(k4 * 4 + kk) * 64 + d];
                w1[kk] = Ws1[(k4 * 4 + kk) * 64 + d];
                w2[kk] = Ws2[(k4 * 4 + kk) * 64 + d];
            }
#pragma unroll
            for (int r = 0; r < 8; ++r) {
                const f4 xv = ((const f4*)xs)[(g * 8 + r) * 16 + k4];
                a0[r] = fmaf(xv.x, w0[0], fmaf(xv.y, w0[1], fmaf(xv.z, w0[2], fmaf(xv.w, w0[3], a0[r]))));
                a1[r] = fmaf(xv.x, w1[0], fmaf(xv.y, w1[1], fmaf(xv.z, w1[2], fmaf(xv.w, w1[3], a1[r]))));
                a2[r] = fmaf(xv.x, w2[0], fmaf(xv.y, w2[1], fmaf(xv.z, w2[2], fmaf(xv.w, w2[3], a2[r]))));
            }
        }
#pragma unroll
        for (int r = 0; r < 8; ++r) {
            Q[(rb + g * 8 + r) * 64 + d] = a0[r];
            K[(rb + g * 8 + r) * 64 + d] = a1[r];
            V[(rb + g * 8 + r) * 64 + d] = a2[r];
        }
    }
}

// ---------- node-to-node self attention (512 thr): x_hat = softmax(QK^T/8) @ V ----------
__global__ __launch_bounds__(512) void selfattn_kernel(
    const float* __restrict__ Q, const float* __restrict__ K,
    const float* __restrict__ V, float* __restrict__ xhat)
{
    const int row = blockIdx.x;            // b*512 + n
    const int b = row >> 9;
    const int t = threadIdx.x;
    __shared__ float qr[64];
    __shared__ float p[512];
    __shared__ float red[512];
    if (t < 64) qr[t] = Q[row * 64 + t];
    __syncthreads();

    {
        const int m = t;
        const f4* kr = (const f4*)(K + (size_t)(b * NN + m) * 64);
        const f4* qq = (const f4*)qr;
        float sp[4] = {0.f, 0.f, 0.f, 0.f};
#pragma unroll
        for (int u = 0; u < 16; ++u) {
            const f4 w = kr[u];
            const f4 qv = qq[u];
            sp[u & 3] += qv.x * w.x + qv.y * w.y + qv.z * w.z + qv.w * w.w;
        }
        p[m] = ((sp[0] + sp[1]) + (sp[2] + sp[3])) * 0.125f;
    }
    __syncthreads();

    const int lane = t & 63, w = t >> 6;
    const float v0 = p[t];
    float m = v0;
#pragma unroll
    for (int o = 1; o < 64; o <<= 1) m = fmaxf(m, __shfl_xor(m, o));
    if (lane == 0) red[w] = m;
    __syncthreads();
    float mx = red[0];
#pragma unroll
    for (int z = 1; z < 8; ++z) mx = fmaxf(mx, red[z]);
    const float e0 = expf(v0 - mx);
    float ss = e0;
#pragma unroll
    for (int o = 1; o < 64; o <<= 1) ss += __shfl_xor(ss, o);
    if (lane == 0) red[8 + w] = ss;
    __syncthreads();
    const float inv = 1.f / (red[8] + red[9] + red[10] + red[11]
                           + red[12] + red[13] + red[14] + red[15]);
    p[t] = e0;
    __syncthreads();

    const int d = t & 63, q = t >> 6;
    float acc = 0.f;
    const int j0 = q * 64;
    for (int j = j0; j < j0 + 64; ++j)
        acc = fmaf(p[j], V[(b * NN + j) * 64 + d], acc);
    red[t] = acc;
    __syncthreads();
    if (t < 64) {
        float s8 = 0.f;
#pragma unroll
        for (int z = 0; z < 8; ++z) s8 += red[t + z * 64];
        xhat[row * 64 + t] = s8 * inv;
    }
}

// ---------------- fused affine maps of xhat: Qn, Vn, P, VnWke, VnWve, q0 ----------------
__global__ __launch_bounds__(256) void affine5_kernel(
    const float* __restrict__ xhat,
    const float* __restrict__ Wqn, const float* __restrict__ bqn,
    const float* __restrict__ Wvn, const float* __restrict__ bvn,
    const float* __restrict__ M_P, const float* __restrict__ c_P,
    const float* __restrict__ M_ke, const float* __restrict__ c_ke,
    const float* __restrict__ M_ve, const float* __restrict__ c_ve,
    const float* __restrict__ vq0, const float* __restrict__ s0p,
    float* __restrict__ Qn, float* __restrict__ Vn, float* __restrict__ P,
    float* __restrict__ VnWke, float* __restrict__ VnWve, float* __restrict__ q0)
{
    const int t = threadIdx.x;
    const int rb = blockIdx.x * 32;
    const int m = blockIdx.y;
    const float* W; const float* c; float* o;
    if (m == 0)      { W = Wqn;  c = bqn;  o = Qn; }
    else if (m == 1) { W = Wvn;  c = bvn;  o = Vn; }
    else if (m == 2) { W = M_P;  c = c_P;  o = P; }
    else if (m == 3) { W = M_ke; c = c_ke; o = VnWke; }
    else             { W = M_ve; c = c_ve; o = VnWve; }
    __shared__ float Ws[4096], xs[2048], cs[64], vq0s[64];
#pragma unroll
    for (int p = 0; p < 4; ++p) ((f4*)Ws)[p * 256 + t] = ((const f4*)W)[p * 256 + t];
    ((f4*)xs)[t]       = ((const f4*)(xhat + rb * 64))[t];
    ((f4*)xs)[t + 256] = ((const f4*)(xhat + rb * 64))[t + 256];
    if (t < 64) { cs[t] = c[t]; if (m == 0) vq0s[t] = vq0[t]; }
    __syncthreads();

    const int d = t & 63, g = t >> 6;
    float acc[8];
#pragma unroll
    for (int r = 0; r < 8; ++r) acc[r] = cs[d];
    for (int k4 = 0; k4 < 16; ++k4) {
        float w[4];
#pragma unroll
        for (int kk = 0; kk < 4; ++kk) w[kk] = Ws[(k4 * 4 + kk) * 64 + d];
#pragma unroll
        for (int r = 0; r < 8; ++r) {
            const f4 xv = ((const f4*)xs)[(g * 8 + r) * 16 + k4];
            acc[r] = fmaf(xv.x, w[0], fmaf(xv.y, w[1], fmaf(xv.z, w[2], fmaf(xv.w, w[3], acc[r]))));
        }
    }
#pragma unroll
    for (int r = 0; r < 8; ++r) o[(rb + g * 8 + r) * 64 + d] = acc[r];

    if (m == 0) {
        const int row = t >> 3, seg = t & 7;
        float part = 0.f;
#pragma unroll
        for (int kk = 0; kk < 8; ++kk)
            part = fmaf(xs[row * 64 + seg * 8 + kk], vq0s[seg * 8 + kk], part);
        part += __shfl_xor(part, 1);
        part += __shfl_xor(part, 2);
        part += __shfl_xor(part, 4);
        if (seg == 0) q0[rb + row] = part + s0p[0];
    }
}

// ---------- streaming edge pass with ONLINE edge-to-node reductions ----------
// 8192 blocks x 256 thr. Block (bi,jc) handles 64 j's. No max-subtraction needed:
// logits v = ai*(u_j - u_ii) are bounded (|u|<~few), exp is fp32-safe.
// Emits per-block partials E = sum exp(v), G = sum ai*exp(v), W[d] = sum ai*exp(v)*VnWve_j[d].
__global__ __launch_bounds__(256) void edge_kernel(
    const float* __restrict__ e, const float* __restrict__ P,
    const float* __restrict__ q0, const float* __restrict__ Vn,
    const float* __restrict__ Qn, const float* __restrict__ VnWke,
    const float* __restrict__ VnWve,
    float* __restrict__ e_new,
    float* __restrict__ Epart, float* __restrict__ Gpart, float* __restrict__ Wpart)
{
    const int blk = blockIdx.x;
    const int bi = blk >> 3;         // b*512 + i
    const int jc = blk & 7;          // 64-j chunk
    const int b  = bi >> 9;
    const int t  = threadIdx.x;
    const int r  = t >> 4;           // row slot 0..15
    const int k  = t & 15;           // float4 lane

    const float q0i = q0[bi];
    const f4 pi4 = ((const f4*)P)[bi * 16 + k];
    const f4 vi4 = ((const f4*)Vn)[bi * 16 + k];
    const f4 qn4 = ((const f4*)Qn)[bi * 16 + k];
    // u_ii = Qn_i . VnWke_i / 8
    const f4 wi4 = ((const f4*)VnWke)[bi * 16 + k];
    float uii = qn4.x * wi4.x + qn4.y * wi4.y + qn4.z * wi4.z + qn4.w * wi4.w;
    uii += __shfl_xor(uii, 1);
    uii += __shfl_xor(uii, 2);
    uii += __shfl_xor(uii, 4);
    uii += __shfl_xor(uii, 8);
    uii *= 0.125f;

    const f4* erow  = (const f4*)(e     + (size_t)bi * NN * 64);
    f4*       enrow = (f4*)      (e_new + (size_t)bi * NN * 64);
    const f4* Prow  = (const f4*)P     + (size_t)b * NN * 16;
    const f4* Vrow  = (const f4*)Vn    + (size_t)b * NN * 16;
    const f4* Krow  = (const f4*)VnWke + (size_t)b * NN * 16;
    const f4* Wvrow = (const f4*)VnWve + (size_t)b * NN * 16;
    const float* q0b = q0 + b * NN;

    float Eacc = 0.f, Gacc = 0.f;
    f4 Wacc = {0.f, 0.f, 0.f, 0.f};

#pragma unroll
    for (int it = 0; it < 4; ++it) {
        const int j = jc * 64 + it * 16 + r;
        const f4 ev = erow[j * 16 + k];
        const f4 pj = Prow[j * 16 + k];
        const f4 wj = Krow[j * 16 + k];
        float s = ev.x * (pj.x - pi4.x) + ev.y * (pj.y - pi4.y)
                + ev.z * (pj.z - pi4.z) + ev.w * (pj.w - pi4.w);
        float uu = qn4.x * wj.x + qn4.y * wj.y + qn4.z * wj.z + qn4.w * wj.w;
        s  += __shfl_xor(s, 1);  uu += __shfl_xor(uu, 1);
        s  += __shfl_xor(s, 2);  uu += __shfl_xor(uu, 2);
        s  += __shfl_xor(s, 4);  uu += __shfl_xor(uu, 4);
        s  += __shfl_xor(s, 8);  uu += __shfl_xor(uu, 8);
        const float ai = 1.f / (1.f + expf(-(s * 0.125f + q0b[j] - q0i)));
        const f4 vj = Vrow[j * 16 + k];
        f4 en;
        en.x = fmaf(ai, vj.x - vi4.x, vi4.x);
        en.y = fmaf(ai, vj.y - vi4.y, vi4.y);
        en.z = fmaf(ai, vj.z - vi4.z, vi4.z);
        en.w = fmaf(ai, vj.w - vi4.w, vi4.w);
        __builtin_nontemporal_store(en, enrow + j * 16 + k);

        const float ex  = expf(ai * (uu * 0.125f - uii));
        const float aex = ai * ex;
        Eacc += ex;
        Gacc += aex;
        const f4 wv = Wvrow[j * 16 + k];
        Wacc.x = fmaf(aex, wv.x, Wacc.x);
        Wacc.y = fmaf(aex, wv.y, Wacc.y);
        Wacc.z = fmaf(aex, wv.z, Wacc.z);
        Wacc.w = fmaf(aex, wv.w, Wacc.w);
    }

    // cross-row reduce within wave (rows r and r^1 / r^2 are lanes l^16 / l^32)
    Eacc += __shfl_xor(Eacc, 16);  Eacc += __shfl_xor(Eacc, 32);
    Gacc += __shfl_xor(Gacc, 16);  Gacc += __shfl_xor(Gacc, 32);
    Wacc.x += __shfl_xor(Wacc.x, 16);  Wacc.x += __shfl_xor(Wacc.x, 32);
    Wacc.y += __shfl_xor(Wacc.y, 16);  Wacc.y += __shfl_xor(Wacc.y, 32);
    Wacc.z += __shfl_xor(Wacc.z, 16);  Wacc.z += __shfl_xor(Wacc.z, 32);
    Wacc.w += __shfl_xor(Wacc.w, 16);  Wacc.w += __shfl_xor(Wacc.w, 32);

    __shared__ float Wred[4][65];
    __shared__ float EG[8];
    const int l = t & 63, w = t >> 6;
    if (l < 16) {
        Wred[w][l * 4 + 0] = Wacc.x;
        Wred[w][l * 4 + 1] = Wacc.y;
        Wred[w][l * 4 + 2] = Wacc.z;
        Wred[w][l * 4 + 3] = Wacc.w;
        if (l == 0) { EG[w] = Eacc; EG[4 + w] = Gacc; }
    }
    __syncthreads();
    if (t < 64) {
        const float Wsum = Wred[0][t] + Wred[1][t] + Wred[2][t] + Wred[3][t];
        Wpart[((size_t)jc * RR + bi) * 64 + t] = Wsum;
        if (t == 0) {
            Epart[jc * RR + bi] = EG[0] + EG[1] + EG[2] + EG[3];
            Gpart[jc * RR + bi] = EG[4] + EG[5] + EG[6] + EG[7];
        }
    }
}

// ---------- final: combine 8 partials per row -> x_new ----------
__global__ __launch_bounds__(64) void final_kernel(
    const float* __restrict__ Epart, const float* __restrict__ Gpart,
    const float* __restrict__ Wpart, const float* __restrict__ VnWve,
    const float* __restrict__ bve, float* __restrict__ x_new)
{
    const int bi = blockIdx.x;
    const int t = threadIdx.x;
    float Wsum = 0.f;
#pragma unroll
    for (int jc = 0; jc < 8; ++jc)
        Wsum += Wpart[((size_t)jc * RR + bi) * 64 + t];
    float E = 0.f, G = 0.f;
#pragma unroll
    for (int jc = 0; jc < 8; ++jc) {
        E += Epart[jc * RR + bi];
        G += Gpart[jc * RR + bi];
    }
    const float inv = 1.f / E;
    x_new[(size_t)bi * 64 + t] = bve[t] + VnWve[(size_t)bi * 64 + t] * (1.f - G * inv)
                               + Wsum * inv;
}

extern "C" void kernel_launch(void* const* d_in, const int* in_sizes, int n_in,
                              void* d_out, int out_size, void* d_ws, size_t ws_size,
                              hipStream_t stream) {
    const float* x   = (const float*)d_in[0];
    const float* e   = (const float*)d_in[1];
    const float* Wq1 = (const float*)d_in[2];  const float* bq1 = (const float*)d_in[3];
    const float* Wk1 = (const float*)d_in[4];  const float* bk1 = (const float*)d_in[5];
    const float* Wv1 = (const float*)d_in[6];  const float* bv1 = (const float*)d_in[7];
    const float* Wqe = (const float*)d_in[8];  const float* bqe = (const float*)d_in[9];
    const float* Wkn = (const float*)d_in[10]; const float* bkn = (const float*)d_in[11];
    const float* Wvn = (const float*)d_in[12]; const float* bvn = (const float*)d_in[13];
    const float* Wqn = (const float*)d_in[14]; const float* bqn = (const float*)d_in[15];
    const float* Wke = (const float*)d_in[16]; /* bke cancels in softmax */
    const float* Wve = (const float*)d_in[18]; const float* bve = (const float*)d_in[19];

    float* out = (float*)d_out;
    float* x_new = out;                 // (2,512,64)
    float* e_new = out + 2 * NN * 64;   // (2,512,512,64)

    float* ws = (float*)d_ws;
    float* Q     = ws;                  // RR*64 each
    float* K     = Q + RR * 64;
    float* V     = K + RR * 64;
    float* xhat  = V + RR * 64;
    float* Qn    = xhat + RR * 64;
    float* Vn    = Qn + RR * 64;
    float* P     = Vn + RR * 64;
    float* VnWke = P + RR * 64;
    float* VnWve = VnWke + RR * 64;
    float* q0    = VnWve + RR * 64;     // RR
    float* M_P   = q0 + RR;             // 4096 each
    float* M_ke  = M_P + 4096;
    float* M_ve  = M_ke + 4096;
    float* c_P   = M_ve + 4096;         // 64 each
    float* c_ke  = c_P + 64;
    float* c_ve  = c_ke + 64;
    float* vq0   = c_ve + 64;
    float* s0    = vq0 + 64;            // 64 (pad)
    float* Epart = s0 + 64;             // 8*RR
    float* Gpart = Epart + 8 * RR;      // 8*RR
    float* Wpart = Gpart + 8 * RR;      // 8*RR*64

    prep_kernel<<<35, 256, 0, stream>>>(x, Wq1, bq1, Wk1, bk1, Wv1, bv1,
                                        Wkn, bkn, Wvn, bvn, Wqe, bqe, Wke, Wve,
                                        Q, K, V,
                                        M_P, c_P, M_ke, c_ke, M_ve, c_ve, vq0, s0);
    selfattn_kernel<<<RR, 512, 0, stream>>>(Q, K, V, xhat);
    affine5_kernel<<<dim3(32, 5), 256, 0, stream>>>(xhat, Wqn, bqn, Wvn, bvn,
                                                    M_P, c_P, M_ke, c_ke, M_ve, c_ve,
                                                    vq0, s0,
                                                    Qn, Vn, P, VnWke, VnWve, q0);
    edge_kernel<<<RR * 8, 256, 0, stream>>>(e, P, q0, Vn, Qn, VnWke, VnWve,
                                            e_new, Epart, Gpart, Wpart);
    final_kernel<<<RR, 64, 0, stream>>>(Epart, Gpart, Wpart, VnWve, bve, x_new);
}

// Round 12
// 94.209 us; speedup vs baseline: 1.1862x; 1.0096x over previous
//
#include <hip/hip_runtime.h>
#include <math.h>

// B=2, N=512, D=64, DH=64
#define NN 512
#define RR 1024   // 2*NN rows

typedef float f4 __attribute__((ext_vector_type(4)));

// ---------------- prep: blocks 0-2 = weight-product precompute; blocks 3-34 = proj3 ----------------
__global__ __launch_bounds__(256) void prep_kernel(
    const float* __restrict__ x,
    const float* __restrict__ Wq1, const float* __restrict__ bq1,
    const float* __restrict__ Wk1, const float* __restrict__ bk1,
    const float* __restrict__ Wv1, const float* __restrict__ bv1,
    const float* __restrict__ Wkn, const float* __restrict__ bkn,
    const float* __restrict__ Wvn, const float* __restrict__ bvn,
    const float* __restrict__ Wqe, const float* __restrict__ bqe,
    const float* __restrict__ Wke, const float* __restrict__ Wve,
    float* __restrict__ Q, float* __restrict__ K, float* __restrict__ V,
    float* __restrict__ M_P, float* __restrict__ c_P,
    float* __restrict__ M_ke, float* __restrict__ c_ke,
    float* __restrict__ M_ve, float* __restrict__ c_ve,
    float* __restrict__ vq0, float* __restrict__ s0p)
{
    __shared__ float sh[14528];
    const int t = threadIdx.x;

    if (blockIdx.x < 3) {
        const int m = blockIdx.x;
        float* As = sh;
        float* Bs = sh + 4160;
        float* va = sh + 8320;
        float* vb = sh + 8384;
        const float* A  = (m == 0) ? Wkn : Wvn;
        const float* aV = (m == 0) ? bkn : bvn;
        const float* B  = (m == 0) ? Wqe : (m == 1 ? Wke : Wve);
#pragma unroll
        for (int p = 0; p < 16; ++p) {
            const int idx = p * 256 + t;
            const int r = idx >> 6, cc = idx & 63;
            As[r * 65 + cc] = A[idx];
            if (m == 0) Bs[r * 65 + cc] = B[idx];
            else        Bs[cc * 65 + r] = B[idx];
        }
        if (t < 64) { va[t] = aV[t]; vb[t] = bqe[t]; }
        __syncthreads();

        const int b = t & 63, g = t >> 6;
        float acc[16];
#pragma unroll
        for (int aa = 0; aa < 16; ++aa) acc[aa] = 0.f;
        for (int k = 0; k < 64; ++k) {
            const float bv = Bs[b * 65 + k];
#pragma unroll
            for (int aa = 0; aa < 16; ++aa)
                acc[aa] = fmaf(As[(g * 16 + aa) * 65 + k], bv, acc[aa]);
        }
        float* M = (m == 0) ? M_P : (m == 1 ? M_ke : M_ve);
#pragma unroll
        for (int aa = 0; aa < 16; ++aa)
            M[(g * 16 + aa) * 64 + b] = acc[aa];

        if (t < 64) {
            float cb = 0.f;
            for (int k = 0; k < 64; ++k) cb = fmaf(va[k], Bs[t * 65 + k], cb);
            float* C = (m == 0) ? c_P : (m == 1 ? c_ke : c_ve);
            C[t] = cb;
            if (m == 0) {
                float q = 0.f;
                for (int k = 0; k < 64; ++k) q = fmaf(As[t * 65 + k], vb[k], q);
                vq0[t] = q * 0.125f;
            }
        }
        if (m == 0 && t == 0) {
            float s = 0.f;
            for (int k = 0; k < 64; ++k) s += vb[k] * va[k];
            *s0p = s * 0.125f;
        }
    } else {
        const int rb = (blockIdx.x - 3) * 32;
        float* Ws0 = sh;
        float* Ws1 = sh + 4096;
        float* Ws2 = sh + 8192;
        float* xs  = sh + 12288;
        float* bs0 = sh + 14336;
        float* bs1 = sh + 14400;
        float* bs2 = sh + 14464;
#pragma unroll
        for (int p = 0; p < 4; ++p) {
            const int idx = p * 256 + t;
            ((f4*)Ws0)[idx] = ((const f4*)Wq1)[idx];
            ((f4*)Ws1)[idx] = ((const f4*)Wk1)[idx];
            ((f4*)Ws2)[idx] = ((const f4*)Wv1)[idx];
        }
        ((f4*)xs)[t]       = ((const f4*)(x + rb * 64))[t];
        ((f4*)xs)[t + 256] = ((const f4*)(x + rb * 64))[t + 256];
        if (t < 64) { bs0[t] = bq1[t]; bs1[t] = bk1[t]; bs2[t] = bv1[t]; }
        __syncthreads();

        const int d = t & 63, g = t >> 6;
        float a0[8], a1[8], a2[8];
#pragma unroll
        for (int r = 0; r < 8; ++r) { a0[r] = bs0[d]; a1[r] = bs1[d]; a2[r] = bs2[d]; }
        for (int k4 = 0; k4 < 16; ++k4) {
            float w0[4], w1[4], w2[4];
#pragma unroll
            for (int kk = 0; kk < 4; ++kk) {
                w0[kk] = Ws0[(k4 * 4 + kk) * 64 + d];
                w1[kk] = Ws1[(k4 * 4 + kk) * 64 + d];
                w2[kk] = Ws2[(k4 * 4 + kk) * 64 + d];
            }
#pragma unroll
            for (int r = 0; r < 8; ++r) {
                const f4 xv = ((const f4*)xs)[(g * 8 + r) * 16 + k4];
                a0[r] = fmaf(xv.x, w0[0], fmaf(xv.y, w0[1], fmaf(xv.z, w0[2], fmaf(xv.w, w0[3], a0[r]))));
                a1[r] = fmaf(xv.x, w1[0], fmaf(xv.y, w1[1], fmaf(xv.z, w1[2], fmaf(xv.w, w1[3], a1[r]))));
                a2[r] = fmaf(xv.x, w2[0], fmaf(xv.y, w2[1], fmaf(xv.z, w2[2], fmaf(xv.w, w2[3], a2[r]))));
            }
        }
#pragma unroll
        for (int r = 0; r < 8; ++r) {
            Q[(rb + g * 8 + r) * 64 + d] = a0[r];
            K[(rb + g * 8 + r) * 64 + d] = a1[r];
            V[(rb + g * 8 + r) * 64 + d] = a2[r];
        }
    }
}

// ---------- node-to-node self attention (512 thr): x_hat = softmax(QK^T/8) @ V ----------
__global__ __launch_bounds__(512) void selfattn_kernel(
    const float* __restrict__ Q, const float* __restrict__ K,
    const float* __restrict__ V, float* __restrict__ xhat)
{
    const int row = blockIdx.x;            // b*512 + n
    const int b = row >> 9;
    const int t = threadIdx.x;
    __shared__ float qr[64];
    __shared__ float p[512];
    __shared__ float red[512];
    if (t < 64) qr[t] = Q[row * 64 + t];
    __syncthreads();

    {
        const int m = t;
        const f4* kr = (const f4*)(K + (size_t)(b * NN + m) * 64);
        const f4* qq = (const f4*)qr;
        float sp[4] = {0.f, 0.f, 0.f, 0.f};
#pragma unroll
        for (int u = 0; u < 16; ++u) {
            const f4 w = kr[u];
            const f4 qv = qq[u];
            sp[u & 3] += qv.x * w.x + qv.y * w.y + qv.z * w.z + qv.w * w.w;
        }
        p[m] = ((sp[0] + sp[1]) + (sp[2] + sp[3])) * 0.125f;
    }
    __syncthreads();

    const int lane = t & 63, w = t >> 6;
    const float v0 = p[t];
    float m = v0;
#pragma unroll
    for (int o = 1; o < 64; o <<= 1) m = fmaxf(m, __shfl_xor(m, o));
    if (lane == 0) red[w] = m;
    __syncthreads();
    float mx = red[0];
#pragma unroll
    for (int z = 1; z < 8; ++z) mx = fmaxf(mx, red[z]);
    const float e0 = expf(v0 - mx);
    float ss = e0;
#pragma unroll
    for (int o = 1; o < 64; o <<= 1) ss += __shfl_xor(ss, o);
    if (lane == 0) red[8 + w] = ss;
    __syncthreads();
    const float inv = 1.f / (red[8] + red[9] + red[10] + red[11]
                           + red[12] + red[13] + red[14] + red[15]);
    p[t] = e0;
    __syncthreads();

    const int d = t & 63, q = t >> 6;
    float acc = 0.f;
    const int j0 = q * 64;
    for (int j = j0; j < j0 + 64; ++j)
        acc = fmaf(p[j], V[(b * NN + j) * 64 + d], acc);
    red[t] = acc;
    __syncthreads();
    if (t < 64) {
        float s8 = 0.f;
#pragma unroll
        for (int z = 0; z < 8; ++z) s8 += red[t + z * 64];
        xhat[row * 64 + t] = s8 * inv;
    }
}

// ---------------- fused affine maps of xhat: Qn, Vn, P, VnWke, VnWve, q0 ----------------
__global__ __launch_bounds__(256) void affine5_kernel(
    const float* __restrict__ xhat,
    const float* __restrict__ Wqn, const float* __restrict__ bqn,
    const float* __restrict__ Wvn, const float* __restrict__ bvn,
    const float* __restrict__ M_P, const float* __restrict__ c_P,
    const float* __restrict__ M_ke, const float* __restrict__ c_ke,
    const float* __restrict__ M_ve, const float* __restrict__ c_ve,
    const float* __restrict__ vq0, const float* __restrict__ s0p,
    float* __restrict__ Qn, float* __restrict__ Vn, float* __restrict__ P,
    float* __restrict__ VnWke, float* __restrict__ VnWve, float* __restrict__ q0)
{
    const int t = threadIdx.x;
    const int rb = blockIdx.x * 32;
    const int m = blockIdx.y;
    const float* W; const float* c; float* o;
    if (m == 0)      { W = Wqn;  c = bqn;  o = Qn; }
    else if (m == 1) { W = Wvn;  c = bvn;  o = Vn; }
    else if (m == 2) { W = M_P;  c = c_P;  o = P; }
    else if (m == 3) { W = M_ke; c = c_ke; o = VnWke; }
    else             { W = M_ve; c = c_ve; o = VnWve; }
    __shared__ float Ws[4096], xs[2048], cs[64], vq0s[64];
#pragma unroll
    for (int p = 0; p < 4; ++p) ((f4*)Ws)[p * 256 + t] = ((const f4*)W)[p * 256 + t];
    ((f4*)xs)[t]       = ((const f4*)(xhat + rb * 64))[t];
    ((f4*)xs)[t + 256] = ((const f4*)(xhat + rb * 64))[t + 256];
    if (t < 64) { cs[t] = c[t]; if (m == 0) vq0s[t] = vq0[t]; }
    __syncthreads();

    const int d = t & 63, g = t >> 6;
    float acc[8];
#pragma unroll
    for (int r = 0; r < 8; ++r) acc[r] = cs[d];
    for (int k4 = 0; k4 < 16; ++k4) {
        float w[4];
#pragma unroll
        for (int kk = 0; kk < 4; ++kk) w[kk] = Ws[(k4 * 4 + kk) * 64 + d];
#pragma unroll
        for (int r = 0; r < 8; ++r) {
            const f4 xv = ((const f4*)xs)[(g * 8 + r) * 16 + k4];
            acc[r] = fmaf(xv.x, w[0], fmaf(xv.y, w[1], fmaf(xv.z, w[2], fmaf(xv.w, w[3], acc[r]))));
        }
    }
#pragma unroll
    for (int r = 0; r < 8; ++r) o[(rb + g * 8 + r) * 64 + d] = acc[r];

    if (m == 0) {
        const int row = t >> 3, seg = t & 7;
        float part = 0.f;
#pragma unroll
        for (int kk = 0; kk < 8; ++kk)
            part = fmaf(xs[row * 64 + seg * 8 + kk], vq0s[seg * 8 + kk], part);
        part += __shfl_xor(part, 1);
        part += __shfl_xor(part, 2);
        part += __shfl_xor(part, 4);
        if (seg == 0) q0[rb + row] = part + s0p[0];
    }
}

// ---------- streaming edge pass with ONLINE edge-to-node reductions ----------
// 8192 blocks x 256 thr. Explicit 4-deep HBM prefetch (named regs), 128-VGPR budget.
__global__ __launch_bounds__(256, 4) void edge_kernel(
    const float* __restrict__ e, const float* __restrict__ P,
    const float* __restrict__ q0, const float* __restrict__ Vn,
    const float* __restrict__ Qn, const float* __restrict__ VnWke,
    const float* __restrict__ VnWve,
    float* __restrict__ e_new,
    float* __restrict__ Epart, float* __restrict__ Gpart, float* __restrict__ Wpart)
{
    const int blk = blockIdx.x;
    const int bi = blk >> 3;         // b*512 + i
    const int jc = blk & 7;          // 64-j chunk
    const int b  = bi >> 9;
    const int t  = threadIdx.x;
    const int r  = t >> 4;           // row slot 0..15
    const int k  = t & 15;           // float4 lane

    const f4* erow  = (const f4*)(e     + (size_t)bi * NN * 64);
    f4*       enrow = (f4*)      (e_new + (size_t)bi * NN * 64);
    const f4* Prow  = (const f4*)P     + (size_t)b * NN * 16;
    const f4* Vrow  = (const f4*)Vn    + (size_t)b * NN * 16;
    const f4* Krow  = (const f4*)VnWke + (size_t)b * NN * 16;
    const f4* Wvrow = (const f4*)VnWve + (size_t)b * NN * 16;
    const float* q0b = q0 + b * NN;

    const int j0 = jc * 64 + r;
    const int j1 = j0 + 16, j2 = j0 + 32, j3 = j0 + 48;

    // ---- HBM prefetch: all 4 e-loads issued before anything depends on them ----
    const f4 ev0 = erow[j0 * 16 + k];
    const f4 ev1 = erow[j1 * 16 + k];
    const f4 ev2 = erow[j2 * 16 + k];
    const f4 ev3 = erow[j3 * 16 + k];

    const float q0i = q0[bi];
    const f4 pi4 = ((const f4*)P)[bi * 16 + k];
    const f4 vi4 = ((const f4*)Vn)[bi * 16 + k];
    const f4 qn4 = ((const f4*)Qn)[bi * 16 + k];
    const f4 wi4 = ((const f4*)VnWke)[bi * 16 + k];
    float uii = qn4.x * wi4.x + qn4.y * wi4.y + qn4.z * wi4.z + qn4.w * wi4.w;
    uii += __shfl_xor(uii, 1);
    uii += __shfl_xor(uii, 2);
    uii += __shfl_xor(uii, 4);
    uii += __shfl_xor(uii, 8);
    uii *= 0.125f;

    float Eacc = 0.f, Gacc = 0.f;
    f4 Wacc = {0.f, 0.f, 0.f, 0.f};

#define EDGE_ITER(EV, J)                                                        \
    {                                                                           \
        const f4 pj = Prow[(J) * 16 + k];                                       \
        const f4 wj = Krow[(J) * 16 + k];                                       \
        const f4 vj = Vrow[(J) * 16 + k];                                       \
        const f4 wv = Wvrow[(J) * 16 + k];                                      \
        const float qj = q0b[(J)];                                              \
        float s = EV.x * (pj.x - pi4.x) + EV.y * (pj.y - pi4.y)                 \
                + EV.z * (pj.z - pi4.z) + EV.w * (pj.w - pi4.w);                \
        float uu = qn4.x * wj.x + qn4.y * wj.y + qn4.z * wj.z + qn4.w * wj.w;   \
        s  += __shfl_xor(s, 1);  uu += __shfl_xor(uu, 1);                       \
        s  += __shfl_xor(s, 2);  uu += __shfl_xor(uu, 2);                       \
        s  += __shfl_xor(s, 4);  uu += __shfl_xor(uu, 4);                       \
        s  += __shfl_xor(s, 8);  uu += __shfl_xor(uu, 8);                       \
        const float ai = 1.f / (1.f + expf(-(s * 0.125f + qj - q0i)));          \
        f4 en;                                                                  \
        en.x = fmaf(ai, vj.x - vi4.x, vi4.x);                                   \
        en.y = fmaf(ai, vj.y - vi4.y, vi4.y);                                   \
        en.z = fmaf(ai, vj.z - vi4.z, vi4.z);                                   \
        en.w = fmaf(ai, vj.w - vi4.w, vi4.w);                                   \
        __builtin_nontemporal_store(en, enrow + (J) * 16 + k);                  \
        const float ex  = expf(ai * (uu * 0.125f - uii));                       \
        const float aex = ai * ex;                                              \
        Eacc += ex;                                                             \
        Gacc += aex;                                                            \
        Wacc.x = fmaf(aex, wv.x, Wacc.x);                                       \
        Wacc.y = fmaf(aex, wv.y, Wacc.y);                                       \
        Wacc.z = fmaf(aex, wv.z, Wacc.z);                                       \
        Wacc.w = fmaf(aex, wv.w, Wacc.w);                                       \
    }

    EDGE_ITER(ev0, j0)
    EDGE_ITER(ev1, j1)
    EDGE_ITER(ev2, j2)
    EDGE_ITER(ev3, j3)
#undef EDGE_ITER

    // cross-row reduce within wave (rows r and r^1 / r^2 are lanes l^16 / l^32)
    Eacc += __shfl_xor(Eacc, 16);  Eacc += __shfl_xor(Eacc, 32);
    Gacc += __shfl_xor(Gacc, 16);  Gacc += __shfl_xor(Gacc, 32);
    Wacc.x += __shfl_xor(Wacc.x, 16);  Wacc.x += __shfl_xor(Wacc.x, 32);
    Wacc.y += __shfl_xor(Wacc.y, 16);  Wacc.y += __shfl_xor(Wacc.y, 32);
    Wacc.z += __shfl_xor(Wacc.z, 16);  Wacc.z += __shfl_xor(Wacc.z, 32);
    Wacc.w += __shfl_xor(Wacc.w, 16);  Wacc.w += __shfl_xor(Wacc.w, 32);

    __shared__ float Wred[4][65];
    __shared__ float EG[8];
    const int l = t & 63, w = t >> 6;
    if (l < 16) {
        Wred[w][l * 4 + 0] = Wacc.x;
        Wred[w][l * 4 + 1] = Wacc.y;
        Wred[w][l * 4 + 2] = Wacc.z;
        Wred[w][l * 4 + 3] = Wacc.w;
        if (l == 0) { EG[w] = Eacc; EG[4 + w] = Gacc; }
    }
    __syncthreads();
    if (t < 64) {
        const float Wsum = Wred[0][t] + Wred[1][t] + Wred[2][t] + Wred[3][t];
        Wpart[((size_t)jc * RR + bi) * 64 + t] = Wsum;
        if (t == 0) {
            Epart[jc * RR + bi] = EG[0] + EG[1] + EG[2] + EG[3];
            Gpart[jc * RR + bi] = EG[4] + EG[5] + EG[6] + EG[7];
        }
    }
}

// ---------- final: combine 8 partials per row -> x_new ----------
__global__ __launch_bounds__(64) void final_kernel(
    const float* __restrict__ Epart, const float* __restrict__ Gpart,
    const float* __restrict__ Wpart, const float* __restrict__ VnWve,
    const float* __restrict__ bve, float* __restrict__ x_new)
{
    const int bi = blockIdx.x;
    const int t = threadIdx.x;
    float Wsum = 0.f;
#pragma unroll
    for (int jc = 0; jc < 8; ++jc)
        Wsum += Wpart[((size_t)jc * RR + bi) * 64 + t];
    float E = 0.f, G = 0.f;
#pragma unroll
    for (int jc = 0; jc < 8; ++jc) {
        E += Epart[jc * RR + bi];
        G += Gpart[jc * RR + bi];
    }
    const float inv = 1.f / E;
    x_new[(size_t)bi * 64 + t] = bve[t] + VnWve[(size_t)bi * 64 + t] * (1.f - G * inv)
                               + Wsum * inv;
}

extern "C" void kernel_launch(void* const* d_in, const int* in_sizes, int n_in,
                              void* d_out, int out_size, void* d_ws, size_t ws_size,
                              hipStream_t stream) {
    const float* x   = (const float*)d_in[0];
    const float* e   = (const float*)d_in[1];
    const float* Wq1 = (const float*)d_in[2];  const float* bq1 = (const float*)d_in[3];
    const float* Wk1 = (const float*)d_in[4];  const float* bk1 = (const float*)d_in[5];
    const float* Wv1 = (const float*)d_in[6];  const float* bv1 = (const float*)d_in[7];
    const float* Wqe = (const float*)d_in[8];  const float* bqe = (const float*)d_in[9];
    const float* Wkn = (const float*)d_in[10]; const float* bkn = (const float*)d_in[11];
    const float* Wvn = (const float*)d_in[12]; const float* bvn = (const float*)d_in[13];
    const float* Wqn = (const float*)d_in[14]; const float* bqn = (const float*)d_in[15];
    const float* Wke = (const float*)d_in[16]; /* bke cancels in softmax */
    const float* Wve = (const float*)d_in[18]; const float* bve = (const float*)d_in[19];

    float* out = (float*)d_out;
    float* x_new = out;                 // (2,512,64)
    float* e_new = out + 2 * NN * 64;   // (2,512,512,64)

    float* ws = (float*)d_ws;
    float* Q     = ws;                  // RR*64 each
    float* K     = Q + RR * 64;
    float* V     = K + RR * 64;
    float* xhat  = V + RR * 64;
    float* Qn    = xhat + RR * 64;
    float* Vn    = Qn + RR * 64;
    float* P     = Vn + RR * 64;
    float* VnWke = P + RR * 64;
    float* VnWve = VnWke + RR * 64;
    float* q0    = VnWve + RR * 64;     // RR
    float* M_P   = q0 + RR;             // 4096 each
    float* M_ke  = M_P + 4096;
    float* M_ve  = M_ke + 4096;
    float* c_P   = M_ve + 4096;         // 64 each
    float* c_ke  = c_P + 64;
    float* c_ve  = c_ke + 64;
    float* vq0   = c_ve + 64;
    float* s0    = vq0 + 64;            // 64 (pad)
    float* Epart = s0 + 64;             // 8*RR
    float* Gpart = Epart + 8 * RR;      // 8*RR
    float* Wpart = Gpart + 8 * RR;      // 8*RR*64

    prep_kernel<<<35, 256, 0, stream>>>(x, Wq1, bq1, Wk1, bk1, Wv1, bv1,
                                        Wkn, bkn, Wvn, bvn, Wqe, bqe, Wke, Wve,
                                        Q, K, V,
                                        M_P, c_P, M_ke, c_ke, M_ve, c_ve, vq0, s0);
    selfattn_kernel<<<RR, 512, 0, stream>>>(Q, K, V, xhat);
    affine5_kernel<<<dim3(32, 5), 256, 0, stream>>>(xhat, Wqn, bqn, Wvn, bvn,
                                                    M_P, c_P, M_ke, c_ke, M_ve, c_ve,
                                                    vq0, s0,
                                                    Qn, Vn, P, VnWke, VnWve, q0);
    edge_kernel<<<RR * 8, 256, 0, stream>>>(e, P, q0, Vn, Qn, VnWke, VnWve,
                                            e_new, Epart, Gpart, Wpart);
    final_kernel<<<RR, 64, 0, stream>>>(Epart, Gpart, Wpart, VnWve, bve, x_new);
}